// Round 11
// baseline (6479.607 us; speedup 1.0000x reference)
//
#include <hip/hip_runtime.h>
#include <hip/hip_bf16.h>

typedef __attribute__((ext_vector_type(8))) short bf16x8;
typedef __attribute__((ext_vector_type(4))) float f32x4;

#define NPIX 8192      // 8 * 32 * 32
#define HIDC 512
#define CIN  2048

// ---------- helpers ----------
__device__ __forceinline__ ushort f2b(float f) {
    union { float f; unsigned u; } v; v.f = f;
    unsigned r = v.u + 0x7fffu + ((v.u >> 16) & 1u);   // RNE
    return (ushort)(r >> 16);
}
__device__ __forceinline__ float b2f(ushort u) {
    union { unsigned u; float f; } v; v.u = ((unsigned)u) << 16; return v.f;
}

__device__ __forceinline__ void gload16(const void* g, void* l) {
    __builtin_amdgcn_global_load_lds(
        (const __attribute__((address_space(1))) void*)g,
        (__attribute__((address_space(3))) void*)l, 16, 0, 0);
}

#define WAITV4() asm volatile("s_waitcnt vmcnt(4)" ::: "memory")
#define WAITV0() asm volatile("s_waitcnt vmcnt(0)" ::: "memory")
#define BAR() do { asm volatile("s_barrier" ::: "memory"); \
                   __builtin_amdgcn_sched_barrier(0); } while (0)

// ---------- 0: zero only the halo border cells of xp ----------
__global__ void zero_border(ushort* __restrict__ xp) {
    int c = blockIdx.x;        // 0..131
    int b = blockIdx.y;        // 0..7
    int y, x;
    if (c < 34)      { y = 0;  x = c; }
    else if (c < 68) { y = 33; x = c - 34; }
    else if (c < 100){ y = c - 68 + 1; x = 0; }
    else             { y = c - 100 + 1; x = 33; }
    uint4* dst = (uint4*)(xp + (((size_t)b * 34 + y) * 34 + x) * CIN);
    uint4 z = {0u, 0u, 0u, 0u};
    dst[threadIdx.x] = z;
}

// ---------- 1: NCHW fp32 -> padded NHWC bf16  xp[b][y+1][x+1][c] ----------
__global__ void pack_x(const float* __restrict__ x, ushort* __restrict__ xp) {
    __shared__ float tile[64][65];
    int b  = blockIdx.z;
    int c0 = blockIdx.y * 64;
    int p0 = blockIdx.x * 64;
    int t = threadIdx.x;
    int tx = t & 63, ty = t >> 6;
    const float* src = x + ((size_t)b * CIN + c0) * 1024 + p0;
    for (int i = ty; i < 64; i += 4)
        tile[i][tx] = src[(size_t)i * 1024 + tx];
    __syncthreads();
    int ci = t & 63, pj = t >> 6;
    for (int j = pj; j < 64; j += 4) {
        int p = p0 + j;
        int y = p >> 5, xx = p & 31;
        ushort* dst = xp + (((size_t)b * 34 + y + 1) * 34 + (xx + 1)) * CIN + c0;
        dst[ci] = f2b(tile[ci][j]);
    }
}

// ---------- 2: w[n][c][ky][kx] fp32 -> wpk[tap][n][c] bf16 ----------
__global__ void pack_w(const float* __restrict__ hw, ushort* __restrict__ wpk) {
    __shared__ float ld[512 * 9];
    int n = blockIdx.x;
    int t = threadIdx.x;
    const float* src = hw + (size_t)n * (CIN * 9);
    for (int cc0 = 0; cc0 < CIN; cc0 += 512) {
        for (int i = t; i < 4608; i += 256) ld[i] = src[(size_t)cc0 * 9 + i];
        __syncthreads();
        for (int t9 = 0; t9 < 9; ++t9)
            for (int idx = t; idx < 512; idx += 256)
                wpk[((size_t)(t9 * 512 + n)) * CIN + cc0 + idx] = f2b(ld[idx * 9 + t9]);
        __syncthreads();
    }
}

// ---------- 3: conf_w/reg_w -> w2b[48][512] bf16 (rows 45..47 zero) ----------
__global__ void pack_w2(const float* __restrict__ cw, const float* __restrict__ rw,
                        ushort* __restrict__ w2b) {
    int i = blockIdx.x * 256 + threadIdx.x;
    if (i >= 48 * 512) return;
    int m = i >> 9, c = i & 511;
    float v = 0.f;
    if (m < 9) v = cw[m * 512 + c];
    else if (m < 45) v = rw[(m - 9) * 512 + c];
    w2b[i] = f2b(v);
}

// ======== 4a: conv implicit GEMM, 256x256 tile, 8 waves (2Mx4N), BK=64 ========
// A double-buffer (2x32K) + B ring-3 (3x32K) = 160 KB LDS (full CU pool).
// Staging: A(i+1) issued at tile(i) start (1-tile lead), B(i+2) mid-tile
// (2-tile lead). Tile-entry wait = vmcnt(4): A(i) and B(i) complete, the 4
// newest B(i+2) loads stay in flight -- vmcnt never drains to 0 mid-loop.
// Freerun interior (no phase fences; compiler pipelines ds_read under MFMA
// with counted lgkmcnt). setprio biases scheduler toward MFMA waves.
// LDS chunk swizzle: stored chunk = dataChunk ^ (row&7); dest linear,
// source pre-XOR'd, read applies XOR (conflict-free, verified r3-r10).
#define NT_TILES 72    // 4608 / 64
#define KSPLIT   4608

__launch_bounds__(512, 2)
__global__ void conv_gemm_splitk(const ushort* __restrict__ xp, const ushort* __restrict__ wpk,
                                 ushort* __restrict__ pp) {
    __shared__ __align__(16) ushort A0[256 * 64];   // 32 KB each
    __shared__ __align__(16) ushort A1[256 * 64];
    __shared__ __align__(16) ushort B0[256 * 64];
    __shared__ __align__(16) ushort B1[256 * 64];
    __shared__ __align__(16) ushort B2[256 * 64];

    int t = threadIdx.x;

    // 256 blocks; xcd = bid&7 -> (nt, ks): 32 blocks of one XCD share one
    // 2.4 MB B-panel (L2-resident) and sweep all 32 M-tiles.
    int bid = blockIdx.x;
    int xcd = bid & 7;
    int nt = xcd & 1, ks = xcd >> 1;
    int mt = bid >> 3;                 // 0..31
    int pix0 = mt * 256, n0 = nt * 256;

    int w = t >> 6, l = t & 63;
    int wr = w >> 2;                   // 0..1 : 128-row band
    int wc = w & 3;                    // 0..3 : 64-col band

    // staging geometry: thread t covers rows r0+64j, data chunk (t&7)^(r0&7)
    int r0 = t >> 3;                   // 0..63
    int dOff = ((t & 7) ^ (r0 & 7)) * 8;

    int aRowBase[4];
#pragma unroll
    for (int j = 0; j < 4; ++j) {
        int p = pix0 + r0 + 64 * j;
        int b = p >> 10, py = (p >> 5) & 31, px = p & 31;
        aRowBase[j] = ((b * 34 + py) * 34 + px) * CIN;
    }
    int bRowBase[4];
#pragma unroll
    for (int j = 0; j < 4; ++j)
        bRowBase[j] = (n0 + r0 + 64 * j) * CIN;

    int ksBase = ks * KSPLIT;

    f32x4 zero = {0.f, 0.f, 0.f, 0.f};
    f32x4 acc[8][4];
#pragma unroll
    for (int i = 0; i < 8; ++i)
#pragma unroll
        for (int j = 0; j < 4; ++j) acc[i][j] = zero;

    int lr = l & 15;
    int swz0 = ((l >> 4) ^ (lr & 7)) * 16;          // k-slice 0 chunk
    int swz1 = ((4 + (l >> 4)) ^ (lr & 7)) * 16;    // k-slice 1 chunk
    int abase = (wr * 128 + lr) * 128;
    int bbase = (wc * 64 + lr) * 128;

    auto stageA = [&](int kt, ushort* As) {
        int fk = ksBase + kt * 64;
        int tap = fk >> 11, chc = fk & 2047;
        int dy = tap / 3, dx = tap - dy * 3;
        int aoff = (dy * 34 + dx) * CIN + chc + dOff;
#pragma unroll
        for (int j = 0; j < 4; ++j)
            gload16(xp + aRowBase[j] + aoff, (char*)As + (t + 512 * j) * 16);
    };
    auto stageB = [&](int kt, ushort* Bs) {
        int fk = ksBase + kt * 64;
        int tap = fk >> 11, chc = fk & 2047;
        int boff = tap * (512 * CIN) + chc + dOff;
#pragma unroll
        for (int j = 0; j < 4; ++j)
            gload16(wpk + bRowBase[j] + boff, (char*)Bs + (t + 512 * j) * 16);
    };

    bf16x8 a0[4], a1[4], bf0[4], bf1[4];

    auto ldA = [&](const ushort* As, int mh, int sz, bf16x8* af) {
#pragma unroll
        for (int m = 0; m < 4; ++m)
            af[m] = *(const bf16x8*)((const char*)As + abase + (mh * 4 + m) * 2048 + sz);
    };
    auto ldB = [&](const ushort* Bs, int sz, bf16x8* bf) {
#pragma unroll
        for (int ni = 0; ni < 4; ++ni)
            bf[ni] = *(const bf16x8*)((const char*)Bs + bbase + ni * 2048 + sz);
    };
    auto mm = [&](int mh, const bf16x8* af, const bf16x8* bf) {
        __builtin_amdgcn_s_setprio(1);
#pragma unroll
        for (int m = 0; m < 4; ++m)
#pragma unroll
            for (int ni = 0; ni < 4; ++ni)
                acc[mh * 4 + m][ni] = __builtin_amdgcn_mfma_f32_16x16x32_bf16(
                    af[m], bf[ni], acc[mh * 4 + m][ni], 0, 0, 0);
        __builtin_amdgcn_s_setprio(0);
    };

    auto tileBody = [&](int i, ushort* Ac, ushort* Bc, ushort* An, ushort* Bn2) {
        ldB(Bc, swz0, bf0);
        ldA(Ac, 0, swz0, a0);
        if (i + 1 < NT_TILES) stageA(i + 1, An);     // 1-tile lead
        mm(0, a0, bf0);
        ldA(Ac, 1, swz0, a1);
        if (i + 2 < NT_TILES) stageB(i + 2, Bn2);    // 2-tile lead
        mm(1, a1, bf0);
        ldB(Bc, swz1, bf1);
        ldA(Ac, 0, swz1, a0);
        mm(0, a0, bf1);
        ldA(Ac, 1, swz1, a1);
        mm(1, a1, bf1);
    };
    auto tileN = [&](int i, ushort* Ac, ushort* Bc, ushort* An, ushort* Bn2) {
        WAITV4(); BAR();                  // A(i), B(i) landed; B(i+2)-slot 4 newest may fly
        tileBody(i, Ac, Bc, An, Bn2);
    };

    // prologue: issue A(0), B(0), B(1): first entry's vmcnt(4) covers A(0),B(0)
    stageA(0, A0); stageB(0, B0); stageB(1, B1);
    for (int i = 0; i < 66; i += 6) {
        tileN(i,     A0, B0, A1, B2);
        tileN(i + 1, A1, B1, A0, B0);
        tileN(i + 2, A0, B2, A1, B1);
        tileN(i + 3, A1, B0, A0, B2);
        tileN(i + 4, A0, B1, A1, B0);
        tileN(i + 5, A1, B2, A0, B1);
    }
    tileN(66, A0, B0, A1, B2);
    tileN(67, A1, B1, A0, B0);
    tileN(68, A0, B2, A1, B1);
    tileN(69, A1, B0, A0, B2);
    tileN(70, A0, B1, A1, B0);
    WAITV0(); BAR();                      // last tile: drain A(71)
    tileBody(71, A1, B2, A0, B1);         // staging guards skip (i+1,i+2 >= NT)

    // epilogue: bf16 partials
    ushort* dst = pp + (size_t)ks * (NPIX * HIDC);
    int hi = l >> 4;
#pragma unroll
    for (int mi = 0; mi < 8; ++mi) {
#pragma unroll
        for (int ni = 0; ni < 4; ++ni) {
            int col = n0 + wc * 64 + ni * 16 + lr;
#pragma unroll
            for (int r = 0; r < 4; ++r) {
                int row = pix0 + wr * 128 + mi * 16 + hi * 4 + r;
                dst[(size_t)row * HIDC + col] = f2b(acc[mi][ni][r]);
            }
        }
    }
}

// ---------- 4c: fallback single-pass conv (256 thr), if ws too small ----------
#define NKSTEP 576

__launch_bounds__(256, 1)
__global__ void conv_gemm(const ushort* __restrict__ xp, const ushort* __restrict__ wpk,
                          const float* __restrict__ hb, ushort* __restrict__ hidden) {
    __shared__ __align__(16) ushort A0[128 * 32];
    __shared__ __align__(16) ushort B0[128 * 32];
    __shared__ __align__(16) ushort A1[128 * 32];
    __shared__ __align__(16) ushort B1[128 * 32];

    int t = threadIdx.x;
    int orig = blockIdx.x;
    int xcd = orig & 7;
    int ix  = orig >> 3;
    int nb  = ix & 3;
    int pb  = (xcd << 3) + (ix >> 2);
    int n0   = nb * 128;
    int pix0 = pb * 128;

    int w = t >> 6, l = t & 63;
    int wr = w >> 1, wc = w & 1;

    int u  = t ^ ((t >> 3) & 7);
    int rA = u >> 2;
    int kA = (u & 3) * 8;

    int p1 = pix0 + rA, p2 = p1 + 64;
    int b   = p1 >> 10;
    int py1 = (p1 >> 5) & 31, px1 = p1 & 31;
    int py2 = (p2 >> 5) & 31, px2 = p2 & 31;

    size_t aBase1 = ((size_t)b * 34 + py1) * 34 + px1;
    size_t aBase2 = ((size_t)b * 34 + py2) * 34 + px2;

    f32x4 zero = {0.f, 0.f, 0.f, 0.f};
    f32x4 acc[4][4];
#pragma unroll
    for (int i = 0; i < 4; ++i)
#pragma unroll
        for (int j = 0; j < 4; ++j) acc[i][j] = zero;

    int lr = l & 15;
    int kc = l >> 4;
    int sw = ((lr * 4 + kc) ^ ((lr >> 1) & 7)) * 16;

    auto stage = [&](int kk, ushort* As, ushort* Bs) {
        int tap = kk >> 6;
        int c0 = (kk & 63) << 5;
        int dy = tap / 3, dx = tap - dy * 3;
        size_t aoff = (size_t)(dy * 34 + dx) * CIN + kA + c0;
        gload16(xp + aBase1 * CIN + aoff, (char*)As + t * 16);
        gload16(xp + aBase2 * CIN + aoff, (char*)As + 4096 + t * 16);
        const ushort* bp = wpk + ((size_t)(tap * 512) + n0 + rA) * CIN + kA + c0;
        gload16(bp, (char*)Bs + t * 16);
        gload16(bp + (size_t)64 * CIN, (char*)Bs + 4096 + t * 16);
    };

    auto compute = [&](const ushort* As, const ushort* Bs) {
        const char* ab = (const char*)As + wr * 4096 + sw;
        const char* bb = (const char*)Bs + wc * 4096 + sw;
        bf16x8 af[4], bfr[4];
#pragma unroll
        for (int mi = 0; mi < 4; ++mi)
            af[mi] = *(const bf16x8*)(ab + mi * 1024);
#pragma unroll
        for (int ni = 0; ni < 4; ++ni)
            bfr[ni] = *(const bf16x8*)(bb + ni * 1024);
#pragma unroll
        for (int mi = 0; mi < 4; ++mi)
#pragma unroll
            for (int ni = 0; ni < 4; ++ni)
                acc[mi][ni] = __builtin_amdgcn_mfma_f32_16x16x32_bf16(
                    af[mi], bfr[ni], acc[mi][ni], 0, 0, 0);
    };

    stage(0, A0, B0);
    __syncthreads();
    for (int kk = 0; kk < NKSTEP; kk += 2) {
        if (kk + 1 < NKSTEP) stage(kk + 1, A1, B1);
        compute(A0, B0);
        __syncthreads();
        if (kk + 2 < NKSTEP) stage(kk + 2, A0, B0);
        compute(A1, B1);
        __syncthreads();
    }

    int lr4 = (l >> 4) * 4;
#pragma unroll
    for (int mi = 0; mi < 4; ++mi) {
#pragma unroll
        for (int ni = 0; ni < 4; ++ni) {
            int col = n0 + wc * 64 + ni * 16 + lr;
            float bias = hb[col];
#pragma unroll
            for (int r = 0; r < 4; ++r) {
                int row = pix0 + wr * 64 + mi * 16 + lr4 + r;
                float v = acc[mi][ni][r] + bias;
                v = v > 0.f ? v : 0.f;
                hidden[(size_t)row * HIDC + col] = f2b(v);
            }
        }
    }
}

// ---------- 5a: FUSED reduce(4 partials)+bias+relu + 1x1 convs -> g ----------
__launch_bounds__(256)
__global__ void gemm2f(const ushort* __restrict__ pp, const float* __restrict__ hb,
                       const ushort* __restrict__ w2b,
                       const float* __restrict__ cb, const float* __restrict__ rb,
                       float* __restrict__ g) {
    __shared__ __align__(16) ushort W2[48 * 520];
    int t = threadIdx.x;
    const unsigned* src = (const unsigned*)w2b;
    unsigned* dstW = (unsigned*)&W2[0];
    for (int i = t; i < 12288; i += 256) {
        int m = i >> 8, c2 = i & 255;
        dstW[m * 260 + c2] = src[i];
    }
    __syncthreads();
    int w = t >> 6, l = t & 63;
    int p0 = blockIdx.x * 64 + w * 16;
    int lr = l & 15, lk = (l >> 4) * 8;
    const size_t S = (size_t)NPIX * HIDC;
    f32x4 zero = {0.f, 0.f, 0.f, 0.f};
    f32x4 acc[3] = {zero, zero, zero};
    const ushort* hrow = pp + (size_t)(p0 + lr) * HIDC + lk;
#pragma unroll 4
    for (int k0 = 0; k0 < 16; ++k0) {
        bf16x8 a0 = *(const bf16x8*)(hrow + k0 * 32);
        bf16x8 a1 = *(const bf16x8*)(hrow + S + k0 * 32);
        bf16x8 a2 = *(const bf16x8*)(hrow + 2 * S + k0 * 32);
        bf16x8 a3 = *(const bf16x8*)(hrow + 3 * S + k0 * 32);
        bf16x8 a;
#pragma unroll
        for (int j = 0; j < 8; ++j) {
            float v = b2f((ushort)a0[j]) + b2f((ushort)a1[j]) +
                      b2f((ushort)a2[j]) + b2f((ushort)a3[j]) + hb[k0 * 32 + lk + j];
            a[j] = (short)f2b(v > 0.f ? v : 0.f);
        }
#pragma unroll
        for (int ni = 0; ni < 3; ++ni) {
            bf16x8 bb = *(const bf16x8*)&W2[(ni * 16 + lr) * 520 + k0 * 32 + lk];
            acc[ni] = __builtin_amdgcn_mfma_f32_16x16x32_bf16(a, bb, acc[ni], 0, 0, 0);
        }
    }
    int lr4 = (l >> 4) * 4;
#pragma unroll
    for (int ni = 0; ni < 3; ++ni) {
        int m = ni * 16 + lr;
        float bias = (m < 9) ? cb[m] : ((m < 45) ? rb[m - 9] : 0.f);
#pragma unroll
        for (int r = 0; r < 4; ++r) {
            int p = p0 + lr4 + r;
            g[(size_t)p * 48 + m] = acc[ni][r] + bias;
        }
    }
}

// ---------- 5b: plain gemm2 from hidden (fallback path) ----------
__launch_bounds__(256)
__global__ void gemm2(const ushort* __restrict__ hidden, const ushort* __restrict__ w2b,
                      const float* __restrict__ cb, const float* __restrict__ rb,
                      float* __restrict__ g) {
    __shared__ __align__(16) ushort W2[48 * 520];
    int t = threadIdx.x;
    const unsigned* src = (const unsigned*)w2b;
    unsigned* dstW = (unsigned*)&W2[0];
    for (int i = t; i < 12288; i += 256) {
        int m = i >> 8, c2 = i & 255;
        dstW[m * 260 + c2] = src[i];
    }
    __syncthreads();
    int w = t >> 6, l = t & 63;
    int p0 = blockIdx.x * 64 + w * 16;
    int lr = l & 15, lk = (l >> 4) * 8;
    f32x4 zero = {0.f, 0.f, 0.f, 0.f};
    f32x4 acc[3] = {zero, zero, zero};
    const ushort* hrow = hidden + (size_t)(p0 + lr) * HIDC + lk;
#pragma unroll 4
    for (int k0 = 0; k0 < 16; ++k0) {
        bf16x8 a = *(const bf16x8*)(hrow + k0 * 32);
#pragma unroll
        for (int ni = 0; ni < 3; ++ni) {
            bf16x8 bb = *(const bf16x8*)&W2[(ni * 16 + lr) * 520 + k0 * 32 + lk];
            acc[ni] = __builtin_amdgcn_mfma_f32_16x16x32_bf16(a, bb, acc[ni], 0, 0, 0);
        }
    }
    int lr4 = (l >> 4) * 4;
#pragma unroll
    for (int ni = 0; ni < 3; ++ni) {
        int m = ni * 16 + lr;
        float bias = (m < 9) ? cb[m] : ((m < 45) ? rb[m - 9] : 0.f);
#pragma unroll
        for (int r = 0; r < 4; ++r) {
            int p = p0 + lr4 + r;
            g[(size_t)p * 48 + m] = acc[ni][r] + bias;
        }
    }
}

// ---------- 6: proposal math ----------
__global__ void proposals(const float* __restrict__ g, float* __restrict__ out) {
    int i = blockIdx.x * 256 + threadIdx.x;
    if (i >= NPIX * 9) return;
    int p = i / 9, a = i - p * 9;
    int y = (p >> 5) & 31, x = p & 31;
    int si = a / 3, ri = a - si * 3;
    float hA = 2.f * (float)(si + 1);
    float wA = (float)((si + 1) * (ri + 1));

    const float* gp = g + (size_t)p * 48;
    float conf = gp[a];
    float o0 = gp[9 + a * 4 + 0];
    float o1 = gp[9 + a * 4 + 1];
    float o2 = gp[9 + a * 4 + 2];
    float o3 = gp[9 + a * 4 + 3];

    float cx = x + 0.5f, cy = y + 0.5f;
    float x1 = fminf(fmaxf(cx - wA * 0.5f, 0.f), 32.f);
    float y1 = fminf(fmaxf(cy - hA * 0.5f, 0.f), 32.f);
    float x2 = fminf(fmaxf(cx + wA * 0.5f, 0.f), 32.f);
    float y2 = fminf(fmaxf(cy + hA * 0.5f, 0.f), 32.f);
    float aw = x2 - x1, ah = y2 - y1;
    float acx = x1 + aw * 0.5f, acy = y1 + ah * 0.5f;
    float pcx = acx + o0 * aw, pcy = acy + o1 * ah;
    float pw = aw * expf(o2), ph = ah * expf(o3);
    float s = 1.f / (1.f + expf(-conf));

    float* o = out + (size_t)i * 5;
    o[0] = s;
    o[1] = (pcx - pw * 0.5f) * 32.f;
    o[2] = (pcy - ph * 0.5f) * 32.f;
    o[3] = (pcx + pw * 0.5f) * 32.f;
    o[4] = (pcy + ph * 0.5f) * 32.f;
}

extern "C" void kernel_launch(void* const* d_in, const int* in_sizes, int n_in,
                              void* d_out, int out_size, void* d_ws, size_t ws_size,
                              hipStream_t stream) {
    const float* x  = (const float*)d_in[0];
    const float* hw = (const float*)d_in[1];
    const float* hb = (const float*)d_in[2];
    const float* cw = (const float*)d_in[3];
    const float* cb = (const float*)d_in[4];
    const float* rw = (const float*)d_in[5];
    const float* rb = (const float*)d_in[6];
    float* out = (float*)d_out;

    char* ws = (char*)d_ws;
    ushort* xp     = (ushort*)(ws);                 // 8*34*34*2048*2  = 37,879,808
    ushort* wpk    = (ushort*)(ws + 37879808);      // 9*512*2048*2   = 18,874,368
    ushort* hidden = (ushort*)(ws + 56754176);      // 8192*512*2     =  8,388,608
    ushort* w2b    = (ushort*)(ws + 65142784);      // 48*512*2       =     49,152
    float*  g      = (float*)(ws + 65191936);       // 8192*48*4      =  1,572,864
    ushort* pp     = (ushort*)(ws + 66764800);      // 4*8192*512*2   = 33,554,432
    const size_t WS_NEED_SPLITK = 66764800 + 33554432;   // 100,319,232

    hipLaunchKernelGGL(zero_border, dim3(132, 8), dim3(256), 0, stream, xp);
    hipLaunchKernelGGL(pack_x, dim3(16, 32, 8), dim3(256), 0, stream, x, xp);
    hipLaunchKernelGGL(pack_w, dim3(512), dim3(256), 0, stream, hw, wpk);
    hipLaunchKernelGGL(pack_w2, dim3(96), dim3(256), 0, stream, cw, rw, w2b);
    if (ws_size >= WS_NEED_SPLITK) {
        hipLaunchKernelGGL(conv_gemm_splitk, dim3(256), dim3(512), 0, stream, xp, wpk, pp);
        hipLaunchKernelGGL(gemm2f, dim3(128), dim3(256), 0, stream, pp, hb, w2b, cb, rb, g);
    } else {
        hipLaunchKernelGGL(conv_gemm, dim3(256), dim3(256), 0, stream, xp, wpk, hb, hidden);
        hipLaunchKernelGGL(gemm2, dim3(128), dim3(256), 0, stream, hidden, w2b, cb, rb, g);
    }
    hipLaunchKernelGGL(proposals, dim3(288), dim3(256), 0, stream, g, out);
}

// Round 12
// 190.547 us; speedup vs baseline: 34.0053x; 34.0053x over previous
//
#include <hip/hip_runtime.h>
#include <hip/hip_bf16.h>

typedef __attribute__((ext_vector_type(8))) short bf16x8;
typedef __attribute__((ext_vector_type(4))) float f32x4;

#define NPIX 8192      // 8 * 32 * 32
#define HIDC 512
#define CIN  2048

// ---------- helpers ----------
__device__ __forceinline__ ushort f2b(float f) {
    union { float f; unsigned u; } v; v.f = f;
    unsigned r = v.u + 0x7fffu + ((v.u >> 16) & 1u);   // RNE
    return (ushort)(r >> 16);
}
__device__ __forceinline__ float b2f(ushort u) {
    union { unsigned u; float f; } v; v.u = ((unsigned)u) << 16; return v.f;
}

__device__ __forceinline__ void gload16(const void* g, void* l) {
    __builtin_amdgcn_global_load_lds(
        (const __attribute__((address_space(1))) void*)g,
        (__attribute__((address_space(3))) void*)l, 16, 0, 0);
}

#define WAITV0() asm volatile("s_waitcnt vmcnt(0)" ::: "memory")
#define BAR() do { asm volatile("s_barrier" ::: "memory"); \
                   __builtin_amdgcn_sched_barrier(0); } while (0)

// ---------- 0: zero only the halo border cells of xp ----------
__global__ void zero_border(ushort* __restrict__ xp) {
    int c = blockIdx.x;        // 0..131
    int b = blockIdx.y;        // 0..7
    int y, x;
    if (c < 34)      { y = 0;  x = c; }
    else if (c < 68) { y = 33; x = c - 34; }
    else if (c < 100){ y = c - 68 + 1; x = 0; }
    else             { y = c - 100 + 1; x = 33; }
    uint4* dst = (uint4*)(xp + (((size_t)b * 34 + y) * 34 + x) * CIN);
    uint4 z = {0u, 0u, 0u, 0u};
    dst[threadIdx.x] = z;
}

// ---------- 1: NCHW fp32 -> padded NHWC bf16  xp[b][y+1][x+1][c] ----------
__global__ void pack_x(const float* __restrict__ x, ushort* __restrict__ xp) {
    __shared__ float tile[64][65];
    int b  = blockIdx.z;
    int c0 = blockIdx.y * 64;
    int p0 = blockIdx.x * 64;
    int t = threadIdx.x;
    int tx = t & 63, ty = t >> 6;
    const float* src = x + ((size_t)b * CIN + c0) * 1024 + p0;
    for (int i = ty; i < 64; i += 4)
        tile[i][tx] = src[(size_t)i * 1024 + tx];
    __syncthreads();
    int ci = t & 63, pj = t >> 6;
    for (int j = pj; j < 64; j += 4) {
        int p = p0 + j;
        int y = p >> 5, xx = p & 31;
        ushort* dst = xp + (((size_t)b * 34 + y + 1) * 34 + (xx + 1)) * CIN + c0;
        dst[ci] = f2b(tile[ci][j]);
    }
}

// ---------- 2: w[n][c][ky][kx] fp32 -> wpk[tap][n][c] bf16 ----------
__global__ void pack_w(const float* __restrict__ hw, ushort* __restrict__ wpk) {
    __shared__ float ld[512 * 9];
    int n = blockIdx.x;
    int t = threadIdx.x;
    const float* src = hw + (size_t)n * (CIN * 9);
    for (int cc0 = 0; cc0 < CIN; cc0 += 512) {
        for (int i = t; i < 4608; i += 256) ld[i] = src[(size_t)cc0 * 9 + i];
        __syncthreads();
        for (int t9 = 0; t9 < 9; ++t9)
            for (int idx = t; idx < 512; idx += 256)
                wpk[((size_t)(t9 * 512 + n)) * CIN + cc0 + idx] = f2b(ld[idx * 9 + t9]);
        __syncthreads();
    }
}

// ---------- 3: conf_w/reg_w -> w2b[48][512] bf16 (rows 45..47 zero) ----------
__global__ void pack_w2(const float* __restrict__ cw, const float* __restrict__ rw,
                        ushort* __restrict__ w2b) {
    int i = blockIdx.x * 256 + threadIdx.x;
    if (i >= 48 * 512) return;
    int m = i >> 9, c = i & 511;
    float v = 0.f;
    if (m < 9) v = cw[m * 512 + c];
    else if (m < 45) v = rw[(m - 9) * 512 + c];
    w2b[i] = f2b(v);
}

// ======== 4a: conv implicit GEMM, 256x256 tile, 8 waves (2Mx4N), BK=64 ========
// r9 structure (147us known-good: dbuf, one barrier+vmcnt(0)/tile, freerun
// interior) + WAVE-PARITY PHASE STAGGER: odd waves consume k-slice 1 before
// k-slice 0 (accumulation is k-order commutative), desynchronizing the two
// waves per SIMD so one wave's MFMA cluster covers the other's ds_reads.
// Zero extra registers (r11 lesson: acc uses the full 256-reg budget; any
// added live state spills).
// LDS chunk swizzle: stored chunk = dataChunk ^ (row&7); dest linear,
// source pre-XOR'd, read applies XOR (conflict-free, verified r3-r10).
#define NT_TILES 72    // 4608 / 64
#define KSPLIT   4608

__launch_bounds__(512, 2)
__global__ void conv_gemm_splitk(const ushort* __restrict__ xp, const ushort* __restrict__ wpk,
                                 ushort* __restrict__ pp) {
    __shared__ __align__(16) ushort A0[256 * 64];   // 32 KB each
    __shared__ __align__(16) ushort B0[256 * 64];
    __shared__ __align__(16) ushort A1[256 * 64];
    __shared__ __align__(16) ushort B1[256 * 64];

    int t = threadIdx.x;

    // 256 blocks; xcd = bid&7 -> (nt, ks): 32 blocks of one XCD share one
    // 2.4 MB B-panel (L2-resident) and sweep all 32 M-tiles.
    int bid = blockIdx.x;
    int xcd = bid & 7;
    int nt = xcd & 1, ks = xcd >> 1;
    int mt = bid >> 3;                 // 0..31
    int pix0 = mt * 256, n0 = nt * 256;

    int w = t >> 6, l = t & 63;
    int wr = w >> 2;                   // 0..1 : 128-row band
    int wc = w & 3;                    // 0..3 : 64-col band

    // staging geometry: thread t covers rows r0+64j, data chunk (t&7)^(r0&7)
    int r0 = t >> 3;                   // 0..63
    int dOff = ((t & 7) ^ (r0 & 7)) * 8;

    int aRowBase[4];
#pragma unroll
    for (int j = 0; j < 4; ++j) {
        int p = pix0 + r0 + 64 * j;
        int b = p >> 10, py = (p >> 5) & 31, px = p & 31;
        aRowBase[j] = ((b * 34 + py) * 34 + px) * CIN;
    }
    int bRowBase[4];
#pragma unroll
    for (int j = 0; j < 4; ++j)
        bRowBase[j] = (n0 + r0 + 64 * j) * CIN;

    int ksBase = ks * KSPLIT;

    f32x4 zero = {0.f, 0.f, 0.f, 0.f};
    f32x4 acc[8][4];
#pragma unroll
    for (int i = 0; i < 8; ++i)
#pragma unroll
        for (int j = 0; j < 4; ++j) acc[i][j] = zero;

    int lr = l & 15;
    int swzA = ((l >> 4) ^ (lr & 7)) * 16;          // k-slice 0 chunk
    int swzB = ((4 + (l >> 4)) ^ (lr & 7)) * 16;    // k-slice 1 chunk
    // wave-parity stagger: odd waves do k-slice 1 first
    int sz0 = (w & 1) ? swzB : swzA;
    int sz1 = (w & 1) ? swzA : swzB;
    int abase = (wr * 128 + lr) * 128;
    int bbase = (wc * 64 + lr) * 128;

    auto stageA = [&](int kt, ushort* As) {
        int fk = ksBase + kt * 64;
        int tap = fk >> 11, chc = fk & 2047;
        int dy = tap / 3, dx = tap - dy * 3;
        int aoff = (dy * 34 + dx) * CIN + chc + dOff;
#pragma unroll
        for (int j = 0; j < 4; ++j)
            gload16(xp + aRowBase[j] + aoff, (char*)As + (t + 512 * j) * 16);
    };
    auto stageB = [&](int kt, ushort* Bs) {
        int fk = ksBase + kt * 64;
        int tap = fk >> 11, chc = fk & 2047;
        int boff = tap * (512 * CIN) + chc + dOff;
#pragma unroll
        for (int j = 0; j < 4; ++j)
            gload16(wpk + bRowBase[j] + boff, (char*)Bs + (t + 512 * j) * 16);
    };

    bf16x8 a0[4], a1[4], bf0[4], bf1[4];

    auto ldA = [&](const ushort* As, int mh, int sz, bf16x8* af) {
#pragma unroll
        for (int m = 0; m < 4; ++m)
            af[m] = *(const bf16x8*)((const char*)As + abase + (mh * 4 + m) * 2048 + sz);
    };
    auto ldB = [&](const ushort* Bs, int sz, bf16x8* bf) {
#pragma unroll
        for (int ni = 0; ni < 4; ++ni)
            bf[ni] = *(const bf16x8*)((const char*)Bs + bbase + ni * 2048 + sz);
    };
    auto mm = [&](int mh, const bf16x8* af, const bf16x8* bf) {
        __builtin_amdgcn_s_setprio(1);
#pragma unroll
        for (int m = 0; m < 4; ++m)
#pragma unroll
            for (int ni = 0; ni < 4; ++ni)
                acc[mh * 4 + m][ni] = __builtin_amdgcn_mfma_f32_16x16x32_bf16(
                    af[m], bf[ni], acc[mh * 4 + m][ni], 0, 0, 0);
        __builtin_amdgcn_s_setprio(0);
    };

    // per K-tile: freerun interior; compiler pipelines ds_reads under MFMA
    // clusters with counted lgkmcnt. Odd waves traverse k-slices in the
    // opposite order (same set, commutative accumulation).
    auto tile = [&](int i, ushort* Ac, ushort* Bc, ushort* An, ushort* Bn) {
        bool st = (i + 1 < NT_TILES);
        WAITV0(); BAR();                       // buf(i) visible to all waves
        ldB(Bc, sz0, bf0);
        ldA(Ac, 0, sz0, a0);
        if (st) stageA(i + 1, An);
        mm(0, a0, bf0);
        ldA(Ac, 1, sz0, a1);
        if (st) stageB(i + 1, Bn);
        mm(1, a1, bf0);
        ldB(Bc, sz1, bf1);
        ldA(Ac, 0, sz1, a0);
        mm(0, a0, bf1);
        ldA(Ac, 1, sz1, a1);
        mm(1, a1, bf1);
    };

    stageA(0, A0); stageB(0, B0);
    for (int i = 0; i < NT_TILES; i += 2) {
        tile(i,     A0, B0, A1, B1);
        tile(i + 1, A1, B1, A0, B0);
    }

    // epilogue: bf16 partials
    ushort* dst = pp + (size_t)ks * (NPIX * HIDC);
    int hi = l >> 4;
#pragma unroll
    for (int mi = 0; mi < 8; ++mi) {
#pragma unroll
        for (int ni = 0; ni < 4; ++ni) {
            int col = n0 + wc * 64 + ni * 16 + lr;
#pragma unroll
            for (int r = 0; r < 4; ++r) {
                int row = pix0 + wr * 128 + mi * 16 + hi * 4 + r;
                dst[(size_t)row * HIDC + col] = f2b(acc[mi][ni][r]);
            }
        }
    }
}

// ---------- 4c: fallback single-pass conv (256 thr), if ws too small ----------
#define NKSTEP 576

__launch_bounds__(256, 1)
__global__ void conv_gemm(const ushort* __restrict__ xp, const ushort* __restrict__ wpk,
                          const float* __restrict__ hb, ushort* __restrict__ hidden) {
    __shared__ __align__(16) ushort A0[128 * 32];
    __shared__ __align__(16) ushort B0[128 * 32];
    __shared__ __align__(16) ushort A1[128 * 32];
    __shared__ __align__(16) ushort B1[128 * 32];

    int t = threadIdx.x;
    int orig = blockIdx.x;
    int xcd = orig & 7;
    int ix  = orig >> 3;
    int nb  = ix & 3;
    int pb  = (xcd << 3) + (ix >> 2);
    int n0   = nb * 128;
    int pix0 = pb * 128;

    int w = t >> 6, l = t & 63;
    int wr = w >> 1, wc = w & 1;

    int u  = t ^ ((t >> 3) & 7);
    int rA = u >> 2;
    int kA = (u & 3) * 8;

    int p1 = pix0 + rA, p2 = p1 + 64;
    int b   = p1 >> 10;
    int py1 = (p1 >> 5) & 31, px1 = p1 & 31;
    int py2 = (p2 >> 5) & 31, px2 = p2 & 31;

    size_t aBase1 = ((size_t)b * 34 + py1) * 34 + px1;
    size_t aBase2 = ((size_t)b * 34 + py2) * 34 + px2;

    f32x4 zero = {0.f, 0.f, 0.f, 0.f};
    f32x4 acc[4][4];
#pragma unroll
    for (int i = 0; i < 4; ++i)
#pragma unroll
        for (int j = 0; j < 4; ++j) acc[i][j] = zero;

    int lr = l & 15;
    int kc = l >> 4;
    int sw = ((lr * 4 + kc) ^ ((lr >> 1) & 7)) * 16;

    auto stage = [&](int kk, ushort* As, ushort* Bs) {
        int tap = kk >> 6;
        int c0 = (kk & 63) << 5;
        int dy = tap / 3, dx = tap - dy * 3;
        size_t aoff = (size_t)(dy * 34 + dx) * CIN + kA + c0;
        gload16(xp + aBase1 * CIN + aoff, (char*)As + t * 16);
        gload16(xp + aBase2 * CIN + aoff, (char*)As + 4096 + t * 16);
        const ushort* bp = wpk + ((size_t)(tap * 512) + n0 + rA) * CIN + kA + c0;
        gload16(bp, (char*)Bs + t * 16);
        gload16(bp + (size_t)64 * CIN, (char*)Bs + 4096 + t * 16);
    };

    auto compute = [&](const ushort* As, const ushort* Bs) {
        const char* ab = (const char*)As + wr * 4096 + sw;
        const char* bb = (const char*)Bs + wc * 4096 + sw;
        bf16x8 af[4], bfr[4];
#pragma unroll
        for (int mi = 0; mi < 4; ++mi)
            af[mi] = *(const bf16x8*)(ab + mi * 1024);
#pragma unroll
        for (int ni = 0; ni < 4; ++ni)
            bfr[ni] = *(const bf16x8*)(bb + ni * 1024);
#pragma unroll
        for (int mi = 0; mi < 4; ++mi)
#pragma unroll
            for (int ni = 0; ni < 4; ++ni)
                acc[mi][ni] = __builtin_amdgcn_mfma_f32_16x16x32_bf16(
                    af[mi], bfr[ni], acc[mi][ni], 0, 0, 0);
    };

    stage(0, A0, B0);
    __syncthreads();
    for (int kk = 0; kk < NKSTEP; kk += 2) {
        if (kk + 1 < NKSTEP) stage(kk + 1, A1, B1);
        compute(A0, B0);
        __syncthreads();
        if (kk + 2 < NKSTEP) stage(kk + 2, A0, B0);
        compute(A1, B1);
        __syncthreads();
    }

    int lr4 = (l >> 4) * 4;
#pragma unroll
    for (int mi = 0; mi < 4; ++mi) {
#pragma unroll
        for (int ni = 0; ni < 4; ++ni) {
            int col = n0 + wc * 64 + ni * 16 + lr;
            float bias = hb[col];
#pragma unroll
            for (int r = 0; r < 4; ++r) {
                int row = pix0 + wr * 64 + mi * 16 + lr4 + r;
                float v = acc[mi][ni][r] + bias;
                v = v > 0.f ? v : 0.f;
                hidden[(size_t)row * HIDC + col] = f2b(v);
            }
        }
    }
}

// ---------- 5a: FUSED reduce(4 partials)+bias+relu + 1x1 convs -> g ----------
__launch_bounds__(256)
__global__ void gemm2f(const ushort* __restrict__ pp, const float* __restrict__ hb,
                       const ushort* __restrict__ w2b,
                       const float* __restrict__ cb, const float* __restrict__ rb,
                       float* __restrict__ g) {
    __shared__ __align__(16) ushort W2[48 * 520];
    int t = threadIdx.x;
    const unsigned* src = (const unsigned*)w2b;
    unsigned* dstW = (unsigned*)&W2[0];
    for (int i = t; i < 12288; i += 256) {
        int m = i >> 8, c2 = i & 255;
        dstW[m * 260 + c2] = src[i];
    }
    __syncthreads();
    int w = t >> 6, l = t & 63;
    int p0 = blockIdx.x * 64 + w * 16;
    int lr = l & 15, lk = (l >> 4) * 8;
    const size_t S = (size_t)NPIX * HIDC;
    f32x4 zero = {0.f, 0.f, 0.f, 0.f};
    f32x4 acc[3] = {zero, zero, zero};
    const ushort* hrow = pp + (size_t)(p0 + lr) * HIDC + lk;
#pragma unroll 4
    for (int k0 = 0; k0 < 16; ++k0) {
        bf16x8 a0 = *(const bf16x8*)(hrow + k0 * 32);
        bf16x8 a1 = *(const bf16x8*)(hrow + S + k0 * 32);
        bf16x8 a2 = *(const bf16x8*)(hrow + 2 * S + k0 * 32);
        bf16x8 a3 = *(const bf16x8*)(hrow + 3 * S + k0 * 32);
        bf16x8 a;
#pragma unroll
        for (int j = 0; j < 8; ++j) {
            float v = b2f((ushort)a0[j]) + b2f((ushort)a1[j]) +
                      b2f((ushort)a2[j]) + b2f((ushort)a3[j]) + hb[k0 * 32 + lk + j];
            a[j] = (short)f2b(v > 0.f ? v : 0.f);
        }
#pragma unroll
        for (int ni = 0; ni < 3; ++ni) {
            bf16x8 bb = *(const bf16x8*)&W2[(ni * 16 + lr) * 520 + k0 * 32 + lk];
            acc[ni] = __builtin_amdgcn_mfma_f32_16x16x32_bf16(a, bb, acc[ni], 0, 0, 0);
        }
    }
    int lr4 = (l >> 4) * 4;
#pragma unroll
    for (int ni = 0; ni < 3; ++ni) {
        int m = ni * 16 + lr;
        float bias = (m < 9) ? cb[m] : ((m < 45) ? rb[m - 9] : 0.f);
#pragma unroll
        for (int r = 0; r < 4; ++r) {
            int p = p0 + lr4 + r;
            g[(size_t)p * 48 + m] = acc[ni][r] + bias;
        }
    }
}

// ---------- 5b: plain gemm2 from hidden (fallback path) ----------
__launch_bounds__(256)
__global__ void gemm2(const ushort* __restrict__ hidden, const ushort* __restrict__ w2b,
                      const float* __restrict__ cb, const float* __restrict__ rb,
                      float* __restrict__ g) {
    __shared__ __align__(16) ushort W2[48 * 520];
    int t = threadIdx.x;
    const unsigned* src = (const unsigned*)w2b;
    unsigned* dstW = (unsigned*)&W2[0];
    for (int i = t; i < 12288; i += 256) {
        int m = i >> 8, c2 = i & 255;
        dstW[m * 260 + c2] = src[i];
    }
    __syncthreads();
    int w = t >> 6, l = t & 63;
    int p0 = blockIdx.x * 64 + w * 16;
    int lr = l & 15, lk = (l >> 4) * 8;
    f32x4 zero = {0.f, 0.f, 0.f, 0.f};
    f32x4 acc[3] = {zero, zero, zero};
    const ushort* hrow = hidden + (size_t)(p0 + lr) * HIDC + lk;
#pragma unroll 4
    for (int k0 = 0; k0 < 16; ++k0) {
        bf16x8 a = *(const bf16x8*)(hrow + k0 * 32);
#pragma unroll
        for (int ni = 0; ni < 3; ++ni) {
            bf16x8 bb = *(const bf16x8*)&W2[(ni * 16 + lr) * 520 + k0 * 32 + lk];
            acc[ni] = __builtin_amdgcn_mfma_f32_16x16x32_bf16(a, bb, acc[ni], 0, 0, 0);
        }
    }
    int lr4 = (l >> 4) * 4;
#pragma unroll
    for (int ni = 0; ni < 3; ++ni) {
        int m = ni * 16 + lr;
        float bias = (m < 9) ? cb[m] : ((m < 45) ? rb[m - 9] : 0.f);
#pragma unroll
        for (int r = 0; r < 4; ++r) {
            int p = p0 + lr4 + r;
            g[(size_t)p * 48 + m] = acc[ni][r] + bias;
        }
    }
}

// ---------- 6: proposal math ----------
__global__ void proposals(const float* __restrict__ g, float* __restrict__ out) {
    int i = blockIdx.x * 256 + threadIdx.x;
    if (i >= NPIX * 9) return;
    int p = i / 9, a = i - p * 9;
    int y = (p >> 5) & 31, x = p & 31;
    int si = a / 3, ri = a - si * 3;
    float hA = 2.f * (float)(si + 1);
    float wA = (float)((si + 1) * (ri + 1));

    const float* gp = g + (size_t)p * 48;
    float conf = gp[a];
    float o0 = gp[9 + a * 4 + 0];
    float o1 = gp[9 + a * 4 + 1];
    float o2 = gp[9 + a * 4 + 2];
    float o3 = gp[9 + a * 4 + 3];

    float cx = x + 0.5f, cy = y + 0.5f;
    float x1 = fminf(fmaxf(cx - wA * 0.5f, 0.f), 32.f);
    float y1 = fminf(fmaxf(cy - hA * 0.5f, 0.f), 32.f);
    float x2 = fminf(fmaxf(cx + wA * 0.5f, 0.f), 32.f);
    float y2 = fminf(fmaxf(cy + hA * 0.5f, 0.f), 32.f);
    float aw = x2 - x1, ah = y2 - y1;
    float acx = x1 + aw * 0.5f, acy = y1 + ah * 0.5f;
    float pcx = acx + o0 * aw, pcy = acy + o1 * ah;
    float pw = aw * expf(o2), ph = ah * expf(o3);
    float s = 1.f / (1.f + expf(-conf));

    float* o = out + (size_t)i * 5;
    o[0] = s;
    o[1] = (pcx - pw * 0.5f) * 32.f;
    o[2] = (pcy - ph * 0.5f) * 32.f;
    o[3] = (pcx + pw * 0.5f) * 32.f;
    o[4] = (pcy + ph * 0.5f) * 32.f;
}

extern "C" void kernel_launch(void* const* d_in, const int* in_sizes, int n_in,
                              void* d_out, int out_size, void* d_ws, size_t ws_size,
                              hipStream_t stream) {
    const float* x  = (const float*)d_in[0];
    const float* hw = (const float*)d_in[1];
    const float* hb = (const float*)d_in[2];
    const float* cw = (const float*)d_in[3];
    const float* cb = (const float*)d_in[4];
    const float* rw = (const float*)d_in[5];
    const float* rb = (const float*)d_in[6];
    float* out = (float*)d_out;

    char* ws = (char*)d_ws;
    ushort* xp     = (ushort*)(ws);                 // 8*34*34*2048*2  = 37,879,808
    ushort* wpk    = (ushort*)(ws + 37879808);      // 9*512*2048*2   = 18,874,368
    ushort* hidden = (ushort*)(ws + 56754176);      // 8192*512*2     =  8,388,608
    ushort* w2b    = (ushort*)(ws + 65142784);      // 48*512*2       =     49,152
    float*  g      = (float*)(ws + 65191936);       // 8192*48*4      =  1,572,864
    ushort* pp     = (ushort*)(ws + 66764800);      // 4*8192*512*2   = 33,554,432
    const size_t WS_NEED_SPLITK = 66764800 + 33554432;   // 100,319,232

    hipLaunchKernelGGL(zero_border, dim3(132, 8), dim3(256), 0, stream, xp);
    hipLaunchKernelGGL(pack_x, dim3(16, 32, 8), dim3(256), 0, stream, x, xp);
    hipLaunchKernelGGL(pack_w, dim3(512), dim3(256), 0, stream, hw, wpk);
    hipLaunchKernelGGL(pack_w2, dim3(96), dim3(256), 0, stream, cw, rw, w2b);
    if (ws_size >= WS_NEED_SPLITK) {
        hipLaunchKernelGGL(conv_gemm_splitk, dim3(256), dim3(512), 0, stream, xp, wpk, pp);
        hipLaunchKernelGGL(gemm2f, dim3(128), dim3(256), 0, stream, pp, hb, w2b, cb, rb, g);
    } else {
        hipLaunchKernelGGL(conv_gemm, dim3(256), dim3(256), 0, stream, xp, wpk, hb, hidden);
        hipLaunchKernelGGL(gemm2, dim3(128), dim3(256), 0, stream, hidden, w2b, cb, rb, g);
    }
    hipLaunchKernelGGL(proposals, dim3(288), dim3(256), 0, stream, g, out);
}

// Round 13
// 175.413 us; speedup vs baseline: 36.9392x; 1.0863x over previous
//
#include <hip/hip_runtime.h>
#include <hip/hip_bf16.h>

typedef __attribute__((ext_vector_type(8))) short bf16x8;
typedef __attribute__((ext_vector_type(4))) float f32x4;

#define NPIX 8192      // 8 * 32 * 32
#define HIDC 512
#define CIN  2048

// ---------- helpers ----------
__device__ __forceinline__ ushort f2b(float f) {
    union { float f; unsigned u; } v; v.f = f;
    unsigned r = v.u + 0x7fffu + ((v.u >> 16) & 1u);   // RNE
    return (ushort)(r >> 16);
}
__device__ __forceinline__ float b2f(ushort u) {
    union { unsigned u; float f; } v; v.u = ((unsigned)u) << 16; return v.f;
}

__device__ __forceinline__ void gload16(const void* g, void* l) {
    __builtin_amdgcn_global_load_lds(
        (const __attribute__((address_space(1))) void*)g,
        (__attribute__((address_space(3))) void*)l, 16, 0, 0);
}

#define WAITV0() asm volatile("s_waitcnt vmcnt(0)" ::: "memory")
#define BAR() do { asm volatile("s_barrier" ::: "memory"); \
                   __builtin_amdgcn_sched_barrier(0); } while (0)

// ---------- 0: FUSED prep: zero_border + pack_x + pack_w + pack_w2 ----------
// grid layout (one dispatch, branch by block range; per-block uniform):
//   [0, 4096)        pack_x   (16 x 32 x 8)
//   [4096, 4608)     pack_w   (512)
//   [4608, 4704)     pack_w2  (96)
//   [4704, 5760)     zero_border (132 x 8)
__global__ void prep(const float* __restrict__ x, ushort* __restrict__ xp,
                     const float* __restrict__ hw, ushort* __restrict__ wpk,
                     const float* __restrict__ cw, const float* __restrict__ rw,
                     ushort* __restrict__ w2b) {
    __shared__ float tile[64][65];      // pack_x
    __shared__ float ld[512 * 9];       // pack_w
    int bid = blockIdx.x;
    int t = threadIdx.x;

    if (bid < 4096) {
        // ---- pack_x: NCHW fp32 -> padded NHWC bf16 ----
        int bx = bid & 15, by = (bid >> 4) & 31, b = bid >> 9;
        int c0 = by * 64;
        int p0 = bx * 64;
        int tx = t & 63, ty = t >> 6;
        const float* src = x + ((size_t)b * CIN + c0) * 1024 + p0;
        for (int i = ty; i < 64; i += 4)
            tile[i][tx] = src[(size_t)i * 1024 + tx];
        __syncthreads();
        int ci = t & 63, pj = t >> 6;
        for (int j = pj; j < 64; j += 4) {
            int p = p0 + j;
            int y = p >> 5, xx = p & 31;
            ushort* dst = xp + (((size_t)b * 34 + y + 1) * 34 + (xx + 1)) * CIN + c0;
            dst[ci] = f2b(tile[ci][j]);
        }
    } else if (bid < 4608) {
        // ---- pack_w: w[n][c][ky][kx] fp32 -> wpk[tap][n][c] bf16 ----
        int n = bid - 4096;
        const float* src = hw + (size_t)n * (CIN * 9);
        for (int cc0 = 0; cc0 < CIN; cc0 += 512) {
            for (int i = t; i < 4608; i += 256) ld[i] = src[(size_t)cc0 * 9 + i];
            __syncthreads();
            for (int t9 = 0; t9 < 9; ++t9)
                for (int idx = t; idx < 512; idx += 256)
                    wpk[((size_t)(t9 * 512 + n)) * CIN + cc0 + idx] = f2b(ld[idx * 9 + t9]);
            __syncthreads();
        }
    } else if (bid < 4704) {
        // ---- pack_w2: conf_w/reg_w -> w2b[48][512] bf16 (rows 45..47 zero) ----
        int i = (bid - 4608) * 256 + t;
        int m = i >> 9, c = i & 511;
        float v = 0.f;
        if (m < 9) v = cw[m * 512 + c];
        else if (m < 45) v = rw[(m - 9) * 512 + c];
        w2b[i] = f2b(v);
    } else {
        // ---- zero_border: halo cells of xp ----
        int r = bid - 4704;
        int c = r % 132, b = r / 132;
        int y, xx;
        if (c < 34)      { y = 0;  xx = c; }
        else if (c < 68) { y = 33; xx = c - 34; }
        else if (c < 100){ y = c - 68 + 1; xx = 0; }
        else             { y = c - 100 + 1; xx = 33; }
        uint4* dst = (uint4*)(xp + (((size_t)b * 34 + y) * 34 + xx) * CIN);
        uint4 z = {0u, 0u, 0u, 0u};
        dst[t] = z;
    }
}

// ======== 4a: conv implicit GEMM, 256x256 tile, 8 waves (2Mx4N), BK=64 ========
// r12 kernel kept byte-identical (147us known-good): dbuf, one barrier +
// vmcnt(0) per K-tile, freerun interior, setprio, wave-parity stagger,
// conflict-free XOR chunk swizzle (stored chunk = dataChunk ^ (row&7);
// dest linear, source pre-XOR'd, read applies XOR).
#define NT_TILES 72    // 4608 / 64
#define KSPLIT   4608

__launch_bounds__(512, 2)
__global__ void conv_gemm_splitk(const ushort* __restrict__ xp, const ushort* __restrict__ wpk,
                                 ushort* __restrict__ pp) {
    __shared__ __align__(16) ushort A0[256 * 64];   // 32 KB each
    __shared__ __align__(16) ushort B0[256 * 64];
    __shared__ __align__(16) ushort A1[256 * 64];
    __shared__ __align__(16) ushort B1[256 * 64];

    int t = threadIdx.x;

    int bid = blockIdx.x;
    int xcd = bid & 7;
    int nt = xcd & 1, ks = xcd >> 1;
    int mt = bid >> 3;                 // 0..31
    int pix0 = mt * 256, n0 = nt * 256;

    int w = t >> 6, l = t & 63;
    int wr = w >> 2;                   // 0..1 : 128-row band
    int wc = w & 3;                    // 0..3 : 64-col band

    int r0 = t >> 3;                   // 0..63
    int dOff = ((t & 7) ^ (r0 & 7)) * 8;

    int aRowBase[4];
#pragma unroll
    for (int j = 0; j < 4; ++j) {
        int p = pix0 + r0 + 64 * j;
        int b = p >> 10, py = (p >> 5) & 31, px = p & 31;
        aRowBase[j] = ((b * 34 + py) * 34 + px) * CIN;
    }
    int bRowBase[4];
#pragma unroll
    for (int j = 0; j < 4; ++j)
        bRowBase[j] = (n0 + r0 + 64 * j) * CIN;

    int ksBase = ks * KSPLIT;

    f32x4 zero = {0.f, 0.f, 0.f, 0.f};
    f32x4 acc[8][4];
#pragma unroll
    for (int i = 0; i < 8; ++i)
#pragma unroll
        for (int j = 0; j < 4; ++j) acc[i][j] = zero;

    int lr = l & 15;
    int swzA = ((l >> 4) ^ (lr & 7)) * 16;          // k-slice 0 chunk
    int swzB = ((4 + (l >> 4)) ^ (lr & 7)) * 16;    // k-slice 1 chunk
    int sz0 = (w & 1) ? swzB : swzA;
    int sz1 = (w & 1) ? swzA : swzB;
    int abase = (wr * 128 + lr) * 128;
    int bbase = (wc * 64 + lr) * 128;

    auto stageA = [&](int kt, ushort* As) {
        int fk = ksBase + kt * 64;
        int tap = fk >> 11, chc = fk & 2047;
        int dy = tap / 3, dx = tap - dy * 3;
        int aoff = (dy * 34 + dx) * CIN + chc + dOff;
#pragma unroll
        for (int j = 0; j < 4; ++j)
            gload16(xp + aRowBase[j] + aoff, (char*)As + (t + 512 * j) * 16);
    };
    auto stageB = [&](int kt, ushort* Bs) {
        int fk = ksBase + kt * 64;
        int tap = fk >> 11, chc = fk & 2047;
        int boff = tap * (512 * CIN) + chc + dOff;
#pragma unroll
        for (int j = 0; j < 4; ++j)
            gload16(wpk + bRowBase[j] + boff, (char*)Bs + (t + 512 * j) * 16);
    };

    bf16x8 a0[4], a1[4], bf0[4], bf1[4];

    auto ldA = [&](const ushort* As, int mh, int sz, bf16x8* af) {
#pragma unroll
        for (int m = 0; m < 4; ++m)
            af[m] = *(const bf16x8*)((const char*)As + abase + (mh * 4 + m) * 2048 + sz);
    };
    auto ldB = [&](const ushort* Bs, int sz, bf16x8* bf) {
#pragma unroll
        for (int ni = 0; ni < 4; ++ni)
            bf[ni] = *(const bf16x8*)((const char*)Bs + bbase + ni * 2048 + sz);
    };
    auto mm = [&](int mh, const bf16x8* af, const bf16x8* bf) {
        __builtin_amdgcn_s_setprio(1);
#pragma unroll
        for (int m = 0; m < 4; ++m)
#pragma unroll
            for (int ni = 0; ni < 4; ++ni)
                acc[mh * 4 + m][ni] = __builtin_amdgcn_mfma_f32_16x16x32_bf16(
                    af[m], bf[ni], acc[mh * 4 + m][ni], 0, 0, 0);
        __builtin_amdgcn_s_setprio(0);
    };

    auto tile = [&](int i, ushort* Ac, ushort* Bc, ushort* An, ushort* Bn) {
        bool st = (i + 1 < NT_TILES);
        WAITV0(); BAR();                       // buf(i) visible to all waves
        ldB(Bc, sz0, bf0);
        ldA(Ac, 0, sz0, a0);
        if (st) stageA(i + 1, An);
        mm(0, a0, bf0);
        ldA(Ac, 1, sz0, a1);
        if (st) stageB(i + 1, Bn);
        mm(1, a1, bf0);
        ldB(Bc, sz1, bf1);
        ldA(Ac, 0, sz1, a0);
        mm(0, a0, bf1);
        ldA(Ac, 1, sz1, a1);
        mm(1, a1, bf1);
    };

    stageA(0, A0); stageB(0, B0);
    for (int i = 0; i < NT_TILES; i += 2) {
        tile(i,     A0, B0, A1, B1);
        tile(i + 1, A1, B1, A0, B0);
    }

    // epilogue: bf16 partials
    ushort* dst = pp + (size_t)ks * (NPIX * HIDC);
    int hi = l >> 4;
#pragma unroll
    for (int mi = 0; mi < 8; ++mi) {
#pragma unroll
        for (int ni = 0; ni < 4; ++ni) {
            int col = n0 + wc * 64 + ni * 16 + lr;
#pragma unroll
            for (int r = 0; r < 4; ++r) {
                int row = pix0 + wr * 128 + mi * 16 + hi * 4 + r;
                dst[(size_t)row * HIDC + col] = f2b(acc[mi][ni][r]);
            }
        }
    }
}

// ---------- 4c: fallback single-pass conv (256 thr), if ws too small ----------
#define NKSTEP 576

__launch_bounds__(256, 1)
__global__ void conv_gemm(const ushort* __restrict__ xp, const ushort* __restrict__ wpk,
                          const float* __restrict__ hb, ushort* __restrict__ hidden) {
    __shared__ __align__(16) ushort A0[128 * 32];
    __shared__ __align__(16) ushort B0[128 * 32];
    __shared__ __align__(16) ushort A1[128 * 32];
    __shared__ __align__(16) ushort B1[128 * 32];

    int t = threadIdx.x;
    int orig = blockIdx.x;
    int xcd = orig & 7;
    int ix  = orig >> 3;
    int nb  = ix & 3;
    int pb  = (xcd << 3) + (ix >> 2);
    int n0   = nb * 128;
    int pix0 = pb * 128;

    int w = t >> 6, l = t & 63;
    int wr = w >> 1, wc = w & 1;

    int u  = t ^ ((t >> 3) & 7);
    int rA = u >> 2;
    int kA = (u & 3) * 8;

    int p1 = pix0 + rA, p2 = p1 + 64;
    int b   = p1 >> 10;
    int py1 = (p1 >> 5) & 31, px1 = p1 & 31;
    int py2 = (p2 >> 5) & 31, px2 = p2 & 31;

    size_t aBase1 = ((size_t)b * 34 + py1) * 34 + px1;
    size_t aBase2 = ((size_t)b * 34 + py2) * 34 + px2;

    f32x4 zero = {0.f, 0.f, 0.f, 0.f};
    f32x4 acc[4][4];
#pragma unroll
    for (int i = 0; i < 4; ++i)
#pragma unroll
        for (int j = 0; j < 4; ++j) acc[i][j] = zero;

    int lr = l & 15;
    int kc = l >> 4;
    int sw = ((lr * 4 + kc) ^ ((lr >> 1) & 7)) * 16;

    auto stage = [&](int kk, ushort* As, ushort* Bs) {
        int tap = kk >> 6;
        int c0 = (kk & 63) << 5;
        int dy = tap / 3, dx = tap - dy * 3;
        size_t aoff = (size_t)(dy * 34 + dx) * CIN + kA + c0;
        gload16(xp + aBase1 * CIN + aoff, (char*)As + t * 16);
        gload16(xp + aBase2 * CIN + aoff, (char*)As + 4096 + t * 16);
        const ushort* bp = wpk + ((size_t)(tap * 512) + n0 + rA) * CIN + kA + c0;
        gload16(bp, (char*)Bs + t * 16);
        gload16(bp + (size_t)64 * CIN, (char*)Bs + 4096 + t * 16);
    };

    auto compute = [&](const ushort* As, const ushort* Bs) {
        const char* ab = (const char*)As + wr * 4096 + sw;
        const char* bb = (const char*)Bs + wc * 4096 + sw;
        bf16x8 af[4], bfr[4];
#pragma unroll
        for (int mi = 0; mi < 4; ++mi)
            af[mi] = *(const bf16x8*)(ab + mi * 1024);
#pragma unroll
        for (int ni = 0; ni < 4; ++ni)
            bfr[ni] = *(const bf16x8*)(bb + ni * 1024);
#pragma unroll
        for (int mi = 0; mi < 4; ++mi)
#pragma unroll
            for (int ni = 0; ni < 4; ++ni)
                acc[mi][ni] = __builtin_amdgcn_mfma_f32_16x16x32_bf16(
                    af[mi], bfr[ni], acc[mi][ni], 0, 0, 0);
    };

    stage(0, A0, B0);
    __syncthreads();
    for (int kk = 0; kk < NKSTEP; kk += 2) {
        if (kk + 1 < NKSTEP) stage(kk + 1, A1, B1);
        compute(A0, B0);
        __syncthreads();
        if (kk + 2 < NKSTEP) stage(kk + 2, A0, B0);
        compute(A1, B1);
        __syncthreads();
    }

    int lr4 = (l >> 4) * 4;
#pragma unroll
    for (int mi = 0; mi < 4; ++mi) {
#pragma unroll
        for (int ni = 0; ni < 4; ++ni) {
            int col = n0 + wc * 64 + ni * 16 + lr;
            float bias = hb[col];
#pragma unroll
            for (int r = 0; r < 4; ++r) {
                int row = pix0 + wr * 64 + mi * 16 + lr4 + r;
                float v = acc[mi][ni][r] + bias;
                v = v > 0.f ? v : 0.f;
                hidden[(size_t)row * HIDC + col] = f2b(v);
            }
        }
    }
}

// ---------- 5: FUSED reduce(4 partials)+bias+relu + 1x1 convs + proposals ----------
__launch_bounds__(256)
__global__ void gemm2p(const ushort* __restrict__ pp, const float* __restrict__ hb,
                       const ushort* __restrict__ w2b,
                       const float* __restrict__ cb, const float* __restrict__ rb,
                       float* __restrict__ out) {
    __shared__ __align__(16) ushort W2[48 * 520];
    __shared__ float gs[64][52];        // stride 52: 2-way bank pattern (free)
    int t = threadIdx.x;
    const unsigned* src = (const unsigned*)w2b;
    unsigned* dstW = (unsigned*)&W2[0];
    for (int i = t; i < 12288; i += 256) {
        int m = i >> 8, c2 = i & 255;
        dstW[m * 260 + c2] = src[i];
    }
    __syncthreads();
    int w = t >> 6, l = t & 63;
    int p0 = blockIdx.x * 64 + w * 16;
    int lr = l & 15, lk = (l >> 4) * 8;
    const size_t S = (size_t)NPIX * HIDC;
    f32x4 zero = {0.f, 0.f, 0.f, 0.f};
    f32x4 acc[3] = {zero, zero, zero};
    const ushort* hrow = pp + (size_t)(p0 + lr) * HIDC + lk;
#pragma unroll 4
    for (int k0 = 0; k0 < 16; ++k0) {
        bf16x8 a0 = *(const bf16x8*)(hrow + k0 * 32);
        bf16x8 a1 = *(const bf16x8*)(hrow + S + k0 * 32);
        bf16x8 a2 = *(const bf16x8*)(hrow + 2 * S + k0 * 32);
        bf16x8 a3 = *(const bf16x8*)(hrow + 3 * S + k0 * 32);
        bf16x8 a;
#pragma unroll
        for (int j = 0; j < 8; ++j) {
            float v = b2f((ushort)a0[j]) + b2f((ushort)a1[j]) +
                      b2f((ushort)a2[j]) + b2f((ushort)a3[j]) + hb[k0 * 32 + lk + j];
            a[j] = (short)f2b(v > 0.f ? v : 0.f);
        }
#pragma unroll
        for (int ni = 0; ni < 3; ++ni) {
            bf16x8 bb = *(const bf16x8*)&W2[(ni * 16 + lr) * 520 + k0 * 32 + lk];
            acc[ni] = __builtin_amdgcn_mfma_f32_16x16x32_bf16(a, bb, acc[ni], 0, 0, 0);
        }
    }
    int lr4 = (l >> 4) * 4;
#pragma unroll
    for (int ni = 0; ni < 3; ++ni) {
        int m = ni * 16 + lr;
        float bias = (m < 9) ? cb[m] : ((m < 45) ? rb[m - 9] : 0.f);
#pragma unroll
        for (int r = 0; r < 4; ++r)
            gs[w * 16 + lr4 + r][m] = acc[ni][r] + bias;
    }
    __syncthreads();

    // proposals for this block's 64 rows (verbatim math, g from LDS)
    int pbase = blockIdx.x * 64;
    for (int i = t; i < 576; i += 256) {
        int lp = i / 9, a = i - lp * 9;
        int p = pbase + lp;
        int y = (p >> 5) & 31, x = p & 31;
        int si = a / 3, ri = a - si * 3;
        float hA = 2.f * (float)(si + 1);
        float wA = (float)((si + 1) * (ri + 1));

        float conf = gs[lp][a];
        float o0 = gs[lp][9 + a * 4 + 0];
        float o1 = gs[lp][9 + a * 4 + 1];
        float o2 = gs[lp][9 + a * 4 + 2];
        float o3 = gs[lp][9 + a * 4 + 3];

        float cx = x + 0.5f, cy = y + 0.5f;
        float x1 = fminf(fmaxf(cx - wA * 0.5f, 0.f), 32.f);
        float y1 = fminf(fmaxf(cy - hA * 0.5f, 0.f), 32.f);
        float x2 = fminf(fmaxf(cx + wA * 0.5f, 0.f), 32.f);
        float y2 = fminf(fmaxf(cy + hA * 0.5f, 0.f), 32.f);
        float aw = x2 - x1, ah = y2 - y1;
        float acx = x1 + aw * 0.5f, acy = y1 + ah * 0.5f;
        float pcx = acx + o0 * aw, pcy = acy + o1 * ah;
        float pw = aw * expf(o2), ph = ah * expf(o3);
        float s = 1.f / (1.f + expf(-conf));

        float* o = out + (size_t)(p * 9 + a) * 5;
        o[0] = s;
        o[1] = (pcx - pw * 0.5f) * 32.f;
        o[2] = (pcy - ph * 0.5f) * 32.f;
        o[3] = (pcx + pw * 0.5f) * 32.f;
        o[4] = (pcy + ph * 0.5f) * 32.f;
    }
}

// ---------- 5b: plain gemm2 from hidden (fallback path) ----------
__launch_bounds__(256)
__global__ void gemm2(const ushort* __restrict__ hidden, const ushort* __restrict__ w2b,
                      const float* __restrict__ cb, const float* __restrict__ rb,
                      float* __restrict__ g) {
    __shared__ __align__(16) ushort W2[48 * 520];
    int t = threadIdx.x;
    const unsigned* src = (const unsigned*)w2b;
    unsigned* dstW = (unsigned*)&W2[0];
    for (int i = t; i < 12288; i += 256) {
        int m = i >> 8, c2 = i & 255;
        dstW[m * 260 + c2] = src[i];
    }
    __syncthreads();
    int w = t >> 6, l = t & 63;
    int p0 = blockIdx.x * 64 + w * 16;
    int lr = l & 15, lk = (l >> 4) * 8;
    f32x4 zero = {0.f, 0.f, 0.f, 0.f};
    f32x4 acc[3] = {zero, zero, zero};
    const ushort* hrow = hidden + (size_t)(p0 + lr) * HIDC + lk;
#pragma unroll 4
    for (int k0 = 0; k0 < 16; ++k0) {
        bf16x8 a = *(const bf16x8*)(hrow + k0 * 32);
#pragma unroll
        for (int ni = 0; ni < 3; ++ni) {
            bf16x8 bb = *(const bf16x8*)&W2[(ni * 16 + lr) * 520 + k0 * 32 + lk];
            acc[ni] = __builtin_amdgcn_mfma_f32_16x16x32_bf16(a, bb, acc[ni], 0, 0, 0);
        }
    }
    int lr4 = (l >> 4) * 4;
#pragma unroll
    for (int ni = 0; ni < 3; ++ni) {
        int m = ni * 16 + lr;
        float bias = (m < 9) ? cb[m] : ((m < 45) ? rb[m - 9] : 0.f);
#pragma unroll
        for (int r = 0; r < 4; ++r) {
            int p = p0 + lr4 + r;
            g[(size_t)p * 48 + m] = acc[ni][r] + bias;
        }
    }
}

// ---------- 6: standalone proposals (fallback path) ----------
__global__ void proposals(const float* __restrict__ g, float* __restrict__ out) {
    int i = blockIdx.x * 256 + threadIdx.x;
    if (i >= NPIX * 9) return;
    int p = i / 9, a = i - p * 9;
    int y = (p >> 5) & 31, x = p & 31;
    int si = a / 3, ri = a - si * 3;
    float hA = 2.f * (float)(si + 1);
    float wA = (float)((si + 1) * (ri + 1));

    const float* gp = g + (size_t)p * 48;
    float conf = gp[a];
    float o0 = gp[9 + a * 4 + 0];
    float o1 = gp[9 + a * 4 + 1];
    float o2 = gp[9 + a * 4 + 2];
    float o3 = gp[9 + a * 4 + 3];

    float cx = x + 0.5f, cy = y + 0.5f;
    float x1 = fminf(fmaxf(cx - wA * 0.5f, 0.f), 32.f);
    float y1 = fminf(fmaxf(cy - hA * 0.5f, 0.f), 32.f);
    float x2 = fminf(fmaxf(cx + wA * 0.5f, 0.f), 32.f);
    float y2 = fminf(fmaxf(cy + hA * 0.5f, 0.f), 32.f);
    float aw = x2 - x1, ah = y2 - y1;
    float acx = x1 + aw * 0.5f, acy = y1 + ah * 0.5f;
    float pcx = acx + o0 * aw, pcy = acy + o1 * ah;
    float pw = aw * expf(o2), ph = ah * expf(o3);
    float s = 1.f / (1.f + expf(-conf));

    float* o = out + (size_t)i * 5;
    o[0] = s;
    o[1] = (pcx - pw * 0.5f) * 32.f;
    o[2] = (pcy - ph * 0.5f) * 32.f;
    o[3] = (pcx + pw * 0.5f) * 32.f;
    o[4] = (pcy + ph * 0.5f) * 32.f;
}

extern "C" void kernel_launch(void* const* d_in, const int* in_sizes, int n_in,
                              void* d_out, int out_size, void* d_ws, size_t ws_size,
                              hipStream_t stream) {
    const float* x  = (const float*)d_in[0];
    const float* hw = (const float*)d_in[1];
    const float* hb = (const float*)d_in[2];
    const float* cw = (const float*)d_in[3];
    const float* cb = (const float*)d_in[4];
    const float* rw = (const float*)d_in[5];
    const float* rb = (const float*)d_in[6];
    float* out = (float*)d_out;

    char* ws = (char*)d_ws;
    ushort* xp     = (ushort*)(ws);                 // 8*34*34*2048*2  = 37,879,808
    ushort* wpk    = (ushort*)(ws + 37879808);      // 9*512*2048*2   = 18,874,368
    ushort* hidden = (ushort*)(ws + 56754176);      // 8192*512*2     =  8,388,608
    ushort* w2b    = (ushort*)(ws + 65142784);      // 48*512*2       =     49,152
    float*  g      = (float*)(ws + 65191936);       // 8192*48*4      =  1,572,864
    ushort* pp     = (ushort*)(ws + 66764800);      // 4*8192*512*2   = 33,554,432
    const size_t WS_NEED_SPLITK = 66764800 + 33554432;   // 100,319,232

    hipLaunchKernelGGL(prep, dim3(5760), dim3(256), 0, stream,
                       x, xp, hw, wpk, cw, rw, w2b);
    if (ws_size >= WS_NEED_SPLITK) {
        hipLaunchKernelGGL(conv_gemm_splitk, dim3(256), dim3(512), 0, stream, xp, wpk, pp);
        hipLaunchKernelGGL(gemm2p, dim3(128), dim3(256), 0, stream, pp, hb, w2b, cb, rb, out);
    } else {
        hipLaunchKernelGGL(conv_gemm, dim3(256), dim3(256), 0, stream, xp, wpk, hb, hidden);
        hipLaunchKernelGGL(gemm2, dim3(128), dim3(256), 0, stream, hidden, w2b, cb, rb, g);
        hipLaunchKernelGGL(proposals, dim3(288), dim3(256), 0, stream, g, out);
    }
}

// Round 14
// 170.383 us; speedup vs baseline: 38.0296x; 1.0295x over previous
//
#include <hip/hip_runtime.h>
#include <hip/hip_bf16.h>

typedef __attribute__((ext_vector_type(8))) short bf16x8;
typedef __attribute__((ext_vector_type(4))) float f32x4;

#define NPIX 8192      // 8 * 32 * 32
#define HIDC 512
#define CIN  2048

// ---------- helpers ----------
__device__ __forceinline__ ushort f2b(float f) {
    union { float f; unsigned u; } v; v.f = f;
    unsigned r = v.u + 0x7fffu + ((v.u >> 16) & 1u);   // RNE
    return (ushort)(r >> 16);
}
__device__ __forceinline__ float b2f(ushort u) {
    union { unsigned u; float f; } v; v.u = ((unsigned)u) << 16; return v.f;
}

__device__ __forceinline__ void gload16(const void* g, void* l) {
    __builtin_amdgcn_global_load_lds(
        (const __attribute__((address_space(1))) void*)g,
        (__attribute__((address_space(3))) void*)l, 16, 0, 0);
}

#define WAITV0() asm volatile("s_waitcnt vmcnt(0)" ::: "memory")
#define BAR() do { asm volatile("s_barrier" ::: "memory"); \
                   __builtin_amdgcn_sched_barrier(0); } while (0)

// ---------- 0: FUSED prep: zero_border + pack_x + pack_w + pack_w2 ----------
//   [0, 4096)        pack_x   (16 x 32 x 8)
//   [4096, 4608)     pack_w   (512)
//   [4608, 4704)     pack_w2  (96)
//   [4704, 5760)     zero_border (132 x 8)
__global__ void prep(const float* __restrict__ x, ushort* __restrict__ xp,
                     const float* __restrict__ hw, ushort* __restrict__ wpk,
                     const float* __restrict__ cw, const float* __restrict__ rw,
                     ushort* __restrict__ w2b) {
    __shared__ float tile[64][65];      // pack_x
    __shared__ float ld[512 * 9];       // pack_w
    int bid = blockIdx.x;
    int t = threadIdx.x;

    if (bid < 4096) {
        int bx = bid & 15, by = (bid >> 4) & 31, b = bid >> 9;
        int c0 = by * 64;
        int p0 = bx * 64;
        int tx = t & 63, ty = t >> 6;
        const float* src = x + ((size_t)b * CIN + c0) * 1024 + p0;
        for (int i = ty; i < 64; i += 4)
            tile[i][tx] = src[(size_t)i * 1024 + tx];
        __syncthreads();
        int ci = t & 63, pj = t >> 6;
        for (int j = pj; j < 64; j += 4) {
            int p = p0 + j;
            int y = p >> 5, xx = p & 31;
            ushort* dst = xp + (((size_t)b * 34 + y + 1) * 34 + (xx + 1)) * CIN + c0;
            dst[ci] = f2b(tile[ci][j]);
        }
    } else if (bid < 4608) {
        int n = bid - 4096;
        const float* src = hw + (size_t)n * (CIN * 9);
        for (int cc0 = 0; cc0 < CIN; cc0 += 512) {
            for (int i = t; i < 4608; i += 256) ld[i] = src[(size_t)cc0 * 9 + i];
            __syncthreads();
            for (int t9 = 0; t9 < 9; ++t9)
                for (int idx = t; idx < 512; idx += 256)
                    wpk[((size_t)(t9 * 512 + n)) * CIN + cc0 + idx] = f2b(ld[idx * 9 + t9]);
            __syncthreads();
        }
    } else if (bid < 4704) {
        int i = (bid - 4608) * 256 + t;
        int m = i >> 9, c = i & 511;
        float v = 0.f;
        if (m < 9) v = cw[m * 512 + c];
        else if (m < 45) v = rw[(m - 9) * 512 + c];
        w2b[i] = f2b(v);
    } else {
        int r = bid - 4704;
        int c = r % 132, b = r / 132;
        int y, xx;
        if (c < 34)      { y = 0;  xx = c; }
        else if (c < 68) { y = 33; xx = c - 34; }
        else if (c < 100){ y = c - 68 + 1; xx = 0; }
        else             { y = c - 100 + 1; xx = 33; }
        uint4* dst = (uint4*)(xp + (((size_t)b * 34 + y) * 34 + xx) * CIN);
        uint4 z = {0u, 0u, 0u, 0u};
        dst[t] = z;
    }
}

// ======== 4a: conv implicit GEMM, 256x256 tile, 8 waves (2Mx4N), BK=64 ========
// r12 147us structure; r14 deltas: (1) setprio removed (m190: hurts lockstep
// GEMM), (2) stageB(i+1) issued at tile start right after stageA(i+1) --
// longer B prefetch lead, zero register cost.
#define NT_TILES 72    // 4608 / 64
#define KSPLIT   4608

__launch_bounds__(512, 2)
__global__ void conv_gemm_splitk(const ushort* __restrict__ xp, const ushort* __restrict__ wpk,
                                 ushort* __restrict__ pp) {
    __shared__ __align__(16) ushort A0[256 * 64];   // 32 KB each
    __shared__ __align__(16) ushort B0[256 * 64];
    __shared__ __align__(16) ushort A1[256 * 64];
    __shared__ __align__(16) ushort B1[256 * 64];

    int t = threadIdx.x;

    int bid = blockIdx.x;
    int xcd = bid & 7;
    int nt = xcd & 1, ks = xcd >> 1;
    int mt = bid >> 3;                 // 0..31
    int pix0 = mt * 256, n0 = nt * 256;

    int w = t >> 6, l = t & 63;
    int wr = w >> 2;                   // 0..1 : 128-row band
    int wc = w & 3;                    // 0..3 : 64-col band

    int r0 = t >> 3;                   // 0..63
    int dOff = ((t & 7) ^ (r0 & 7)) * 8;

    int aRowBase[4];
#pragma unroll
    for (int j = 0; j < 4; ++j) {
        int p = pix0 + r0 + 64 * j;
        int b = p >> 10, py = (p >> 5) & 31, px = p & 31;
        aRowBase[j] = ((b * 34 + py) * 34 + px) * CIN;
    }
    int bRowBase[4];
#pragma unroll
    for (int j = 0; j < 4; ++j)
        bRowBase[j] = (n0 + r0 + 64 * j) * CIN;

    int ksBase = ks * KSPLIT;

    f32x4 zero = {0.f, 0.f, 0.f, 0.f};
    f32x4 acc[8][4];
#pragma unroll
    for (int i = 0; i < 8; ++i)
#pragma unroll
        for (int j = 0; j < 4; ++j) acc[i][j] = zero;

    int lr = l & 15;
    int swzA = ((l >> 4) ^ (lr & 7)) * 16;          // k-slice 0 chunk
    int swzB = ((4 + (l >> 4)) ^ (lr & 7)) * 16;    // k-slice 1 chunk
    int sz0 = (w & 1) ? swzB : swzA;
    int sz1 = (w & 1) ? swzA : swzB;
    int abase = (wr * 128 + lr) * 128;
    int bbase = (wc * 64 + lr) * 128;

    auto stageA = [&](int kt, ushort* As) {
        int fk = ksBase + kt * 64;
        int tap = fk >> 11, chc = fk & 2047;
        int dy = tap / 3, dx = tap - dy * 3;
        int aoff = (dy * 34 + dx) * CIN + chc + dOff;
#pragma unroll
        for (int j = 0; j < 4; ++j)
            gload16(xp + aRowBase[j] + aoff, (char*)As + (t + 512 * j) * 16);
    };
    auto stageB = [&](int kt, ushort* Bs) {
        int fk = ksBase + kt * 64;
        int tap = fk >> 11, chc = fk & 2047;
        int boff = tap * (512 * CIN) + chc + dOff;
#pragma unroll
        for (int j = 0; j < 4; ++j)
            gload16(wpk + bRowBase[j] + boff, (char*)Bs + (t + 512 * j) * 16);
    };

    bf16x8 a0[4], a1[4], bf0[4], bf1[4];

    auto ldA = [&](const ushort* As, int mh, int sz, bf16x8* af) {
#pragma unroll
        for (int m = 0; m < 4; ++m)
            af[m] = *(const bf16x8*)((const char*)As + abase + (mh * 4 + m) * 2048 + sz);
    };
    auto ldB = [&](const ushort* Bs, int sz, bf16x8* bf) {
#pragma unroll
        for (int ni = 0; ni < 4; ++ni)
            bf[ni] = *(const bf16x8*)((const char*)Bs + bbase + ni * 2048 + sz);
    };
    auto mm = [&](int mh, const bf16x8* af, const bf16x8* bf) {
#pragma unroll
        for (int m = 0; m < 4; ++m)
#pragma unroll
            for (int ni = 0; ni < 4; ++ni)
                acc[mh * 4 + m][ni] = __builtin_amdgcn_mfma_f32_16x16x32_bf16(
                    af[m], bf[ni], acc[mh * 4 + m][ni], 0, 0, 0);
    };

    auto tile = [&](int i, ushort* Ac, ushort* Bc, ushort* An, ushort* Bn) {
        bool st = (i + 1 < NT_TILES);
        WAITV0(); BAR();                       // buf(i) visible to all waves
        ldB(Bc, sz0, bf0);
        ldA(Ac, 0, sz0, a0);
        if (st) { stageA(i + 1, An); stageB(i + 1, Bn); }
        mm(0, a0, bf0);
        ldA(Ac, 1, sz0, a1);
        mm(1, a1, bf0);
        ldB(Bc, sz1, bf1);
        ldA(Ac, 0, sz1, a0);
        mm(0, a0, bf1);
        ldA(Ac, 1, sz1, a1);
        mm(1, a1, bf1);
    };

    stageA(0, A0); stageB(0, B0);
    for (int i = 0; i < NT_TILES; i += 2) {
        tile(i,     A0, B0, A1, B1);
        tile(i + 1, A1, B1, A0, B0);
    }

    // epilogue: bf16 partials
    ushort* dst = pp + (size_t)ks * (NPIX * HIDC);
    int hi = l >> 4;
#pragma unroll
    for (int mi = 0; mi < 8; ++mi) {
#pragma unroll
        for (int ni = 0; ni < 4; ++ni) {
            int col = n0 + wc * 64 + ni * 16 + lr;
#pragma unroll
            for (int r = 0; r < 4; ++r) {
                int row = pix0 + wr * 128 + mi * 16 + hi * 4 + r;
                dst[(size_t)row * HIDC + col] = f2b(acc[mi][ni][r]);
            }
        }
    }
}

// ---------- 4c: fallback single-pass conv (256 thr), if ws too small ----------
#define NKSTEP 576

__launch_bounds__(256, 1)
__global__ void conv_gemm(const ushort* __restrict__ xp, const ushort* __restrict__ wpk,
                          const float* __restrict__ hb, ushort* __restrict__ hidden) {
    __shared__ __align__(16) ushort A0[128 * 32];
    __shared__ __align__(16) ushort B0[128 * 32];
    __shared__ __align__(16) ushort A1[128 * 32];
    __shared__ __align__(16) ushort B1[128 * 32];

    int t = threadIdx.x;
    int orig = blockIdx.x;
    int xcd = orig & 7;
    int ix  = orig >> 3;
    int nb  = ix & 3;
    int pb  = (xcd << 3) + (ix >> 2);
    int n0   = nb * 128;
    int pix0 = pb * 128;

    int w = t >> 6, l = t & 63;
    int wr = w >> 1, wc = w & 1;

    int u  = t ^ ((t >> 3) & 7);
    int rA = u >> 2;
    int kA = (u & 3) * 8;

    int p1 = pix0 + rA, p2 = p1 + 64;
    int b   = p1 >> 10;
    int py1 = (p1 >> 5) & 31, px1 = p1 & 31;
    int py2 = (p2 >> 5) & 31, px2 = p2 & 31;

    size_t aBase1 = ((size_t)b * 34 + py1) * 34 + px1;
    size_t aBase2 = ((size_t)b * 34 + py2) * 34 + px2;

    f32x4 zero = {0.f, 0.f, 0.f, 0.f};
    f32x4 acc[4][4];
#pragma unroll
    for (int i = 0; i < 4; ++i)
#pragma unroll
        for (int j = 0; j < 4; ++j) acc[i][j] = zero;

    int lr = l & 15;
    int kc = l >> 4;
    int sw = ((lr * 4 + kc) ^ ((lr >> 1) & 7)) * 16;

    auto stage = [&](int kk, ushort* As, ushort* Bs) {
        int tap = kk >> 6;
        int c0 = (kk & 63) << 5;
        int dy = tap / 3, dx = tap - dy * 3;
        size_t aoff = (size_t)(dy * 34 + dx) * CIN + kA + c0;
        gload16(xp + aBase1 * CIN + aoff, (char*)As + t * 16);
        gload16(xp + aBase2 * CIN + aoff, (char*)As + 4096 + t * 16);
        const ushort* bp = wpk + ((size_t)(tap * 512) + n0 + rA) * CIN + kA + c0;
        gload16(bp, (char*)Bs + t * 16);
        gload16(bp + (size_t)64 * CIN, (char*)Bs + 4096 + t * 16);
    };

    auto compute = [&](const ushort* As, const ushort* Bs) {
        const char* ab = (const char*)As + wr * 4096 + sw;
        const char* bb = (const char*)Bs + wc * 4096 + sw;
        bf16x8 af[4], bfr[4];
#pragma unroll
        for (int mi = 0; mi < 4; ++mi)
            af[mi] = *(const bf16x8*)(ab + mi * 1024);
#pragma unroll
        for (int ni = 0; ni < 4; ++ni)
            bfr[ni] = *(const bf16x8*)(bb + ni * 1024);
#pragma unroll
        for (int mi = 0; mi < 4; ++mi)
#pragma unroll
            for (int ni = 0; ni < 4; ++ni)
                acc[mi][ni] = __builtin_amdgcn_mfma_f32_16x16x32_bf16(
                    af[mi], bfr[ni], acc[mi][ni], 0, 0, 0);
    };

    stage(0, A0, B0);
    __syncthreads();
    for (int kk = 0; kk < NKSTEP; kk += 2) {
        if (kk + 1 < NKSTEP) stage(kk + 1, A1, B1);
        compute(A0, B0);
        __syncthreads();
        if (kk + 2 < NKSTEP) stage(kk + 2, A0, B0);
        compute(A1, B1);
        __syncthreads();
    }

    int lr4 = (l >> 4) * 4;
#pragma unroll
    for (int mi = 0; mi < 4; ++mi) {
#pragma unroll
        for (int ni = 0; ni < 4; ++ni) {
            int col = n0 + wc * 64 + ni * 16 + lr;
            float bias = hb[col];
#pragma unroll
            for (int r = 0; r < 4; ++r) {
                int row = pix0 + wr * 64 + mi * 16 + lr4 + r;
                float v = acc[mi][ni][r] + bias;
                v = v > 0.f ? v : 0.f;
                hidden[(size_t)row * HIDC + col] = f2b(v);
            }
        }
    }
}

// ---------- 5: FUSED reduce(4)+bias+relu + 1x1 convs + proposals ----------
// 256 blocks x 128 threads (2 waves x 16 rows = 32 rows/block): full-chip
// parallelism on a BW-bound kernel (reads 33.5 MB of pp).
__launch_bounds__(128)
__global__ void gemm2p(const ushort* __restrict__ pp, const float* __restrict__ hb,
                       const ushort* __restrict__ w2b,
                       const float* __restrict__ cb, const float* __restrict__ rb,
                       float* __restrict__ out) {
    __shared__ __align__(16) ushort W2[48 * 520];
    __shared__ float gs[32][52];        // stride 52: 2-way bank pattern (free)
    int t = threadIdx.x;
    const unsigned* src = (const unsigned*)w2b;
    unsigned* dstW = (unsigned*)&W2[0];
    for (int i = t; i < 12288; i += 128) {
        int m = i >> 8, c2 = i & 255;
        dstW[m * 260 + c2] = src[i];
    }
    __syncthreads();
    int w = t >> 6, l = t & 63;
    int p0 = blockIdx.x * 32 + w * 16;
    int lr = l & 15, lk = (l >> 4) * 8;
    const size_t S = (size_t)NPIX * HIDC;
    f32x4 zero = {0.f, 0.f, 0.f, 0.f};
    f32x4 acc[3] = {zero, zero, zero};
    const ushort* hrow = pp + (size_t)(p0 + lr) * HIDC + lk;
#pragma unroll 4
    for (int k0 = 0; k0 < 16; ++k0) {
        bf16x8 a0 = *(const bf16x8*)(hrow + k0 * 32);
        bf16x8 a1 = *(const bf16x8*)(hrow + S + k0 * 32);
        bf16x8 a2 = *(const bf16x8*)(hrow + 2 * S + k0 * 32);
        bf16x8 a3 = *(const bf16x8*)(hrow + 3 * S + k0 * 32);
        bf16x8 a;
#pragma unroll
        for (int j = 0; j < 8; ++j) {
            float v = b2f((ushort)a0[j]) + b2f((ushort)a1[j]) +
                      b2f((ushort)a2[j]) + b2f((ushort)a3[j]) + hb[k0 * 32 + lk + j];
            a[j] = (short)f2b(v > 0.f ? v : 0.f);
        }
#pragma unroll
        for (int ni = 0; ni < 3; ++ni) {
            bf16x8 bb = *(const bf16x8*)&W2[(ni * 16 + lr) * 520 + k0 * 32 + lk];
            acc[ni] = __builtin_amdgcn_mfma_f32_16x16x32_bf16(a, bb, acc[ni], 0, 0, 0);
        }
    }
    int lr4 = (l >> 4) * 4;
#pragma unroll
    for (int ni = 0; ni < 3; ++ni) {
        int m = ni * 16 + lr;
        float bias = (m < 9) ? cb[m] : ((m < 45) ? rb[m - 9] : 0.f);
#pragma unroll
        for (int r = 0; r < 4; ++r)
            gs[w * 16 + lr4 + r][m] = acc[ni][r] + bias;
    }
    __syncthreads();

    // proposals for this block's 32 rows (verbatim math, g from LDS)
    int pbase = blockIdx.x * 32;
    for (int i = t; i < 288; i += 128) {
        int lp = i / 9, a = i - lp * 9;
        int p = pbase + lp;
        int y = (p >> 5) & 31, x = p & 31;
        int si = a / 3, ri = a - si * 3;
        float hA = 2.f * (float)(si + 1);
        float wA = (float)((si + 1) * (ri + 1));

        float conf = gs[lp][a];
        float o0 = gs[lp][9 + a * 4 + 0];
        float o1 = gs[lp][9 + a * 4 + 1];
        float o2 = gs[lp][9 + a * 4 + 2];
        float o3 = gs[lp][9 + a * 4 + 3];

        float cx = x + 0.5f, cy = y + 0.5f;
        float x1 = fminf(fmaxf(cx - wA * 0.5f, 0.f), 32.f);
        float y1 = fminf(fmaxf(cy - hA * 0.5f, 0.f), 32.f);
        float x2 = fminf(fmaxf(cx + wA * 0.5f, 0.f), 32.f);
        float y2 = fminf(fmaxf(cy + hA * 0.5f, 0.f), 32.f);
        float aw = x2 - x1, ah = y2 - y1;
        float acx = x1 + aw * 0.5f, acy = y1 + ah * 0.5f;
        float pcx = acx + o0 * aw, pcy = acy + o1 * ah;
        float pw = aw * expf(o2), ph = ah * expf(o3);
        float s = 1.f / (1.f + expf(-conf));

        float* o = out + (size_t)(p * 9 + a) * 5;
        o[0] = s;
        o[1] = (pcx - pw * 0.5f) * 32.f;
        o[2] = (pcy - ph * 0.5f) * 32.f;
        o[3] = (pcx + pw * 0.5f) * 32.f;
        o[4] = (pcy + ph * 0.5f) * 32.f;
    }
}

// ---------- 5b: plain gemm2 from hidden (fallback path) ----------
__launch_bounds__(256)
__global__ void gemm2(const ushort* __restrict__ hidden, const ushort* __restrict__ w2b,
                      const float* __restrict__ cb, const float* __restrict__ rb,
                      float* __restrict__ g) {
    __shared__ __align__(16) ushort W2[48 * 520];
    int t = threadIdx.x;
    const unsigned* src = (const unsigned*)w2b;
    unsigned* dstW = (unsigned*)&W2[0];
    for (int i = t; i < 12288; i += 256) {
        int m = i >> 8, c2 = i & 255;
        dstW[m * 260 + c2] = src[i];
    }
    __syncthreads();
    int w = t >> 6, l = t & 63;
    int p0 = blockIdx.x * 64 + w * 16;
    int lr = l & 15, lk = (l >> 4) * 8;
    f32x4 zero = {0.f, 0.f, 0.f, 0.f};
    f32x4 acc[3] = {zero, zero, zero};
    const ushort* hrow = hidden + (size_t)(p0 + lr) * HIDC + lk;
#pragma unroll 4
    for (int k0 = 0; k0 < 16; ++k0) {
        bf16x8 a = *(const bf16x8*)(hrow + k0 * 32);
#pragma unroll
        for (int ni = 0; ni < 3; ++ni) {
            bf16x8 bb = *(const bf16x8*)&W2[(ni * 16 + lr) * 520 + k0 * 32 + lk];
            acc[ni] = __builtin_amdgcn_mfma_f32_16x16x32_bf16(a, bb, acc[ni], 0, 0, 0);
        }
    }
    int lr4 = (l >> 4) * 4;
#pragma unroll
    for (int ni = 0; ni < 3; ++ni) {
        int m = ni * 16 + lr;
        float bias = (m < 9) ? cb[m] : ((m < 45) ? rb[m - 9] : 0.f);
#pragma unroll
        for (int r = 0; r < 4; ++r) {
            int p = p0 + lr4 + r;
            g[(size_t)p * 48 + m] = acc[ni][r] + bias;
        }
    }
}

// ---------- 6: standalone proposals (fallback path) ----------
__global__ void proposals(const float* __restrict__ g, float* __restrict__ out) {
    int i = blockIdx.x * 256 + threadIdx.x;
    if (i >= NPIX * 9) return;
    int p = i / 9, a = i - p * 9;
    int y = (p >> 5) & 31, x = p & 31;
    int si = a / 3, ri = a - si * 3;
    float hA = 2.f * (float)(si + 1);
    float wA = (float)((si + 1) * (ri + 1));

    const float* gp = g + (size_t)p * 48;
    float conf = gp[a];
    float o0 = gp[9 + a * 4 + 0];
    float o1 = gp[9 + a * 4 + 1];
    float o2 = gp[9 + a * 4 + 2];
    float o3 = gp[9 + a * 4 + 3];

    float cx = x + 0.5f, cy = y + 0.5f;
    float x1 = fminf(fmaxf(cx - wA * 0.5f, 0.f), 32.f);
    float y1 = fminf(fmaxf(cy - hA * 0.5f, 0.f), 32.f);
    float x2 = fminf(fmaxf(cx + wA * 0.5f, 0.f), 32.f);
    float y2 = fminf(fmaxf(cy + hA * 0.5f, 0.f), 32.f);
    float aw = x2 - x1, ah = y2 - y1;
    float acx = x1 + aw * 0.5f, acy = y1 + ah * 0.5f;
    float pcx = acx + o0 * aw, pcy = acy + o1 * ah;
    float pw = aw * expf(o2), ph = ah * expf(o3);
    float s = 1.f / (1.f + expf(-conf));

    float* o = out + (size_t)i * 5;
    o[0] = s;
    o[1] = (pcx - pw * 0.5f) * 32.f;
    o[2] = (pcy - ph * 0.5f) * 32.f;
    o[3] = (pcx + pw * 0.5f) * 32.f;
    o[4] = (pcy + ph * 0.5f) * 32.f;
}

extern "C" void kernel_launch(void* const* d_in, const int* in_sizes, int n_in,
                              void* d_out, int out_size, void* d_ws, size_t ws_size,
                              hipStream_t stream) {
    const float* x  = (const float*)d_in[0];
    const float* hw = (const float*)d_in[1];
    const float* hb = (const float*)d_in[2];
    const float* cw = (const float*)d_in[3];
    const float* cb = (const float*)d_in[4];
    const float* rw = (const float*)d_in[5];
    const float* rb = (const float*)d_in[6];
    float* out = (float*)d_out;

    char* ws = (char*)d_ws;
    ushort* xp     = (ushort*)(ws);                 // 8*34*34*2048*2  = 37,879,808
    ushort* wpk    = (ushort*)(ws + 37879808);      // 9*512*2048*2   = 18,874,368
    ushort* hidden = (ushort*)(ws + 56754176);      // 8192*512*2     =  8,388,608
    ushort* w2b    = (ushort*)(ws + 65142784);      // 48*512*2       =     49,152
    float*  g      = (float*)(ws + 65191936);       // 8192*48*4      =  1,572,864
    ushort* pp     = (ushort*)(ws + 66764800);      // 4*8192*512*2   = 33,554,432
    const size_t WS_NEED_SPLITK = 66764800 + 33554432;   // 100,319,232

    hipLaunchKernelGGL(prep, dim3(5760), dim3(256), 0, stream,
                       x, xp, hw, wpk, cw, rw, w2b);
    if (ws_size >= WS_NEED_SPLITK) {
        hipLaunchKernelGGL(conv_gemm_splitk, dim3(256), dim3(512), 0, stream, xp, wpk, pp);
        hipLaunchKernelGGL(gemm2p, dim3(256), dim3(128), 0, stream, pp, hb, w2b, cb, rb, out);
    } else {
        hipLaunchKernelGGL(conv_gemm, dim3(256), dim3(256), 0, stream, xp, wpk, hb, hidden);
        hipLaunchKernelGGL(gemm2, dim3(128), dim3(256), 0, stream, hidden, w2b, cb, rb, g);
        hipLaunchKernelGGL(proposals, dim3(288), dim3(256), 0, stream, g, out);
    }
}